// Round 15
// baseline (287.222 us; speedup 1.0000x reference)
//
#include <hip/hip_runtime.h>
#include <hip/hip_fp16.h>
#include <math.h>

// ---------------------------------------------------------------------------
// dual GAT (2 branches x 4 GATConv layers), N=20000 nodes, E=320000 edges.
// R14 = exact R10 (R11/R12/R13 single-wave gather restructures all reverted)
// with ONE decomposition change:
//  - gather128_f: each node's edges split across 2 waves by chunk parity
//    (concurrent full-chunk + tail), LDS-combined. 2x waves, ~2x less
//    exposed latency per node.
//  - gather64_both: the two branch loops run on sibling waves, LDS-combined.
// ---------------------------------------------------------------------------

#define WAVE 64
#define NBKP 320   // padded bucket count (N/64 = 313 actual)

typedef _Float16 f16;
typedef f16 f16x8 __attribute__((ext_vector_type(8)));
typedef f16 f16x4 __attribute__((ext_vector_type(4)));
typedef float f32x4 __attribute__((ext_vector_type(4)));

// ---- stage 1: per-(block,bucket) counts (LDS hist, no global atomics) ----
__global__ __launch_bounds__(256) void bucket_count(
        const int* __restrict__ ei0, const int* __restrict__ ei1,
        int* __restrict__ carr, int nbuk, int E, int tot) {
    __shared__ int h[NBKP];
    int br = blockIdx.y;
    const int* ei = br ? ei1 : ei0;
    for (int i = threadIdx.x; i < NBKP; i += 256) h[i] = 0;
    __syncthreads();
    for (int t = blockIdx.x * 256 + threadIdx.x; t < tot; t += 256 * 256) {
        int dst = (t < E) ? ei[E + t] : (t - E);
        atomicAdd(&h[dst >> 6], 1);
    }
    __syncthreads();
    int* c = carr + ((size_t)br * gridDim.x + blockIdx.x) * NBKP;
    for (int i = threadIdx.x; i < NBKP; i += 256) c[i] = h[i];
}

// ---- stage 2a: per-bucket exclusive prefix over the 256 blocks -----------
__global__ __launch_bounds__(256) void bucket_scan1(
        int* __restrict__ carr, int* __restrict__ btot, int nblk) {
    __shared__ int smem[256];
    int br = blockIdx.y, k = blockIdx.x;
    size_t idx = ((size_t)br * nblk + threadIdx.x) * NBKP + k;
    int v = carr[idx];
    smem[threadIdx.x] = v;
    __syncthreads();
    #pragma unroll
    for (int off = 1; off < 256; off <<= 1) {
        int t = (threadIdx.x >= off) ? smem[threadIdx.x - off] : 0;
        __syncthreads();
        smem[threadIdx.x] += t;
        __syncthreads();
    }
    carr[idx] = smem[threadIdx.x] - v;            // exclusive prefix
    if (threadIdx.x == 255) btot[br * NBKP + k] = smem[255];
}

// ---- stage 2b: bucket bases (512-thread LDS scan over bucket totals) -----
__global__ __launch_bounds__(512) void bucket_scan2(
        const int* __restrict__ btot, int* __restrict__ bbase, int nbuk) {
    __shared__ int smem[512];
    int br = blockIdx.y;
    int v = (threadIdx.x < nbuk) ? btot[br * NBKP + threadIdx.x] : 0;
    smem[threadIdx.x] = v;
    __syncthreads();
    #pragma unroll
    for (int off = 1; off < 512; off <<= 1) {
        int t = (threadIdx.x >= off) ? smem[threadIdx.x - off] : 0;
        __syncthreads();
        smem[threadIdx.x] += t;
        __syncthreads();
    }
    int* bb = bbase + br * (nbuk + 1);
    if (threadIdx.x < nbuk) bb[threadIdx.x] = smem[threadIdx.x] - v;
    if (threadIdx.x == nbuk - 1) bb[nbuk] = smem[threadIdx.x];
}

// ---- stage 3: deterministic-slot pair scatter into bucket regions --------
__global__ __launch_bounds__(256) void bucket_scatter(
        const int* __restrict__ ei0, const int* __restrict__ ei1,
        const int* __restrict__ carr, const int* __restrict__ bbase,
        long long* __restrict__ pbuf, int nbuk, int E, int tot) {
    __shared__ int base_s[NBKP];
    __shared__ int h[NBKP];
    int br = blockIdx.y;
    const int* ei = br ? ei1 : ei0;
    const int* offb = carr + ((size_t)br * gridDim.x + blockIdx.x) * NBKP;
    const int* bb = bbase + br * (nbuk + 1);
    long long* pb = pbuf + (size_t)br * tot;
    for (int i = threadIdx.x; i < NBKP; i += 256) {
        h[i] = 0;
        base_s[i] = (i < nbuk) ? (bb[i] + offb[i]) : 0;
    }
    __syncthreads();
    for (int t = blockIdx.x * 256 + threadIdx.x; t < tot; t += 256 * 256) {
        int src, dst;
        if (t < E) { src = ei[t]; dst = ei[E + t]; }
        else       { src = dst = t - E; }
        int k = dst >> 6;
        int r = atomicAdd(&h[k], 1);        // LDS rank
        pb[base_s[k] + r] = ((long long)dst << 32) | (unsigned)src;
    }
}

// ---- stage 4: per-bucket exact CSR + rowptr ------------------------------
__global__ __launch_bounds__(256) void bucket_finalize(
        const long long* __restrict__ pbuf, const int* __restrict__ bbase,
        int* __restrict__ rowptrb, int* __restrict__ csrb,
        int n, int nbuk, int tot, int np) {
    __shared__ int h64[64], excl[64], cur[64];
    int br = blockIdx.y, k = blockIdx.x;
    const int* bb = bbase + br * (nbuk + 1);
    const long long* pb = pbuf + (size_t)br * tot;
    int base = bb[k], endb = bb[k + 1], cnt = endb - base;
    int* rp = rowptrb + (size_t)br * np;
    int* cs = csrb + (size_t)br * tot;
    int d0 = k << 6;
    int nn = min(64, n - d0);
    if (threadIdx.x < 64) h64[threadIdx.x] = 0;
    __syncthreads();
    for (int i = threadIdx.x; i < cnt; i += 256) {
        int dst = (int)(pb[base + i] >> 32);
        atomicAdd(&h64[dst & 63], 1);
    }
    __syncthreads();
    if (threadIdx.x == 0) {
        int run = 0;
        for (int j = 0; j < 64; ++j) { excl[j] = run; run += h64[j]; }
    }
    __syncthreads();
    if (threadIdx.x < 64) cur[threadIdx.x] = excl[threadIdx.x];
    if (threadIdx.x < nn) rp[d0 + threadIdx.x] = base + excl[threadIdx.x];
    if (k == nbuk - 1 && threadIdx.x == 64) rp[n] = endb;
    __syncthreads();
    for (int i = threadIdx.x; i < cnt; i += 256) {
        long long p = pb[base + i];
        int dst = (int)(p >> 32), src = (int)(p & 0xffffffffLL);
        int slot = atomicAdd(&cur[dst & 63], 1);
        cs[base + slot] = src;
    }
}

// ---- score-weight tiles for ALL layers in one launch ---------------------
struct WsdArgs {
    const float* W[8];    // [layer*2+branch]
    const float* as[8];
    const float* ad[8];
};

__global__ __launch_bounds__(256) void wsd_all(WsdArgs a, f16* __restrict__ wsd) {
    int l = blockIdx.z, b = blockIdx.y;
    int fout = (l == 3) ? 64 : 128;
    int H    = (l == 3) ? 1 : 4;
    int C    = (l == 3) ? 64 : 32;
    const float* W   = a.W[l * 2 + b];
    const float* a_s = a.as[l * 2 + b];
    const float* a_d = a.ad[l * 2 + b];
    f16* out = wsd + ((size_t)(l * 2 + b)) * 16 * 128;
    int k = blockIdx.x * 16 + (threadIdx.x & 15);
    int sc = threadIdx.x >> 4;
    float sum = 0.f;
    if (sc < 2 * H) {
        int hd = (sc < H) ? sc : sc - H;
        const float* av = (sc < H) ? a_s : a_d;
        const float4* Wr = (const float4*)(W + (size_t)k * fout + hd * C);
        const float4* ar = (const float4*)(av + hd * C);
        for (int c = 0; c < (C >> 2); ++c) {
            float4 wv = Wr[c]; float4 a4 = ar[c];
            sum += wv.x * a4.x + wv.y * a4.y + wv.z * a4.z + wv.w * a4.w;
        }
    }
    out[sc * 128 + k] = (f16)sum;
}

// ---- MFMA GEMM: h = x@W (f32 acc, fp16 out) + score cols ----------------
template <typename XT>
__global__ __launch_bounds__(256) void gemm_mfma(
        const XT* __restrict__ x0, const XT* __restrict__ x1,
        const float* __restrict__ W0, const float* __restrict__ W1,
        const f16* __restrict__ wsd,
        f16* __restrict__ hb, float* __restrict__ ssb, float* __restrict__ sdb,
        int n, int fout, int H) {
    __shared__ f16 xl[64 * 136];
    __shared__ f16 wl[80 * 136];
    int b = blockIdx.z;
    const XT* x = b ? x1 : x0;
    const float* W = b ? W1 : W0;
    f16* h = hb + (size_t)b * n * 128;
    float* ss = ssb + (size_t)b * n * 4;
    float* sd = sdb + (size_t)b * n * 4;
    int colbase = blockIdx.y * 64;
    bool last = (blockIdx.y == gridDim.y - 1);
    int lane = threadIdx.x & 63, w = threadIdx.x >> 6;

    {
        int c = threadIdx.x & 63, kb = (threadIdx.x >> 6) * 32;
        #pragma unroll 8
        for (int j = 0; j < 32; ++j)
            wl[c * 136 + kb + j] = (f16)W[(size_t)(kb + j) * fout + colbase + c];
    }
    if (last) {
        int c = threadIdx.x & 15, kb = (threadIdx.x >> 4) * 8;
        *(f16x8*)&wl[(64 + c) * 136 + kb] =
            *(const f16x8*)&wsd[(size_t)b * 2048 + c * 128 + kb];
    }
    __syncthreads();

    f16x8 B[5][4];
    #pragma unroll
    for (int ct = 0; ct < 5; ++ct)
        #pragma unroll
        for (int kc = 0; kc < 4; ++kc)
            B[ct][kc] = *(const f16x8*)
                &wl[(ct * 16 + (lane & 15)) * 136 + kc * 32 + (lane >> 4) * 8];

    for (int base = blockIdx.x * 64; base < n; base += gridDim.x * 64) {
        __syncthreads();
        {
            int r = threadIdx.x >> 2, k0 = (threadIdx.x & 3) * 32;
            int row = base + r;
            if (row < n) {
                if constexpr (sizeof(XT) == 4) {
                    const float4* x4 = (const float4*)x;
                    #pragma unroll
                    for (int j = 0; j < 8; ++j) {
                        float4 v = x4[(size_t)row * 32 + (k0 >> 2) + j];
                        f16x4 hv = {(f16)v.x, (f16)v.y, (f16)v.z, (f16)v.w};
                        *(f16x4*)&xl[r * 136 + k0 + 4 * j] = hv;
                    }
                } else {
                    const f16x8* x8 = (const f16x8*)x;
                    #pragma unroll
                    for (int j = 0; j < 4; ++j)
                        *(f16x8*)&xl[r * 136 + k0 + 8 * j] =
                            x8[(size_t)row * 16 + (k0 >> 3) + j];
                }
            } else {
                f16x4 z = {(f16)0.f, (f16)0.f, (f16)0.f, (f16)0.f};
                #pragma unroll
                for (int j = 0; j < 8; ++j)
                    *(f16x4*)&xl[r * 136 + k0 + 4 * j] = z;
            }
        }
        __syncthreads();

        f16x8 A[4];
        #pragma unroll
        for (int kc = 0; kc < 4; ++kc)
            A[kc] = *(const f16x8*)
                &xl[(w * 16 + (lane & 15)) * 136 + kc * 32 + (lane >> 4) * 8];

        f32x4 acc[5];
        #pragma unroll
        for (int ct = 0; ct < 5; ++ct) acc[ct] = (f32x4){0.f, 0.f, 0.f, 0.f};
        #pragma unroll
        for (int ct = 0; ct < 5; ++ct)
            #pragma unroll
            for (int kc = 0; kc < 4; ++kc)
                acc[ct] = __builtin_amdgcn_mfma_f32_16x16x32_f16(
                    A[kc], B[ct][kc], acc[ct], 0, 0, 0);

        int r0 = base + w * 16 + (lane >> 4) * 4;
        int c0 = lane & 15;
        #pragma unroll
        for (int ct = 0; ct < 4; ++ct) {
            int col = colbase + ct * 16 + c0;
            #pragma unroll
            for (int j = 0; j < 4; ++j) {
                int row = r0 + j;
                if (row < n) h[(size_t)row * fout + col] = (f16)acc[ct][j];
            }
        }
        if (last) {
            #pragma unroll
            for (int j = 0; j < 4; ++j) {
                int row = r0 + j;
                if (row < n) {
                    float v = acc[4][j];
                    if (c0 < H)          ss[(size_t)row * H + c0] = v;
                    else if (c0 < 2 * H) sd[(size_t)row * H + c0 - H] = v;
                }
            }
        }
    }
}

// ---- fused alpha + gather, 128-wide layers (4 heads x 32) ---------------
// 2 waves per node (chunk parity split), LDS-combined; loop body = R10's.
__global__ __launch_bounds__(256) void gather128_f(
        const __half2* __restrict__ h2, const float* __restrict__ ss,
        const float* __restrict__ sd, const int* __restrict__ rowptr,
        const int* __restrict__ csr, const float* __restrict__ bias,
        f16* __restrict__ out, int n) {
    __shared__ float r0s[4][64], r1s[4][64], rds[4][64];
    int wid = threadIdx.x >> 6, lane = threadIdx.x & 63;
    int pair = wid >> 1, half = wid & 1;
    int v = blockIdx.x * 2 + pair;
    bool valid = (v < n);
    int hd = lane >> 4;
    int sub = lane & 15;
    int hd16 = hd * 16;

    float acc0 = 0.f, acc1 = 0.f, den = 0.f;
    if (valid) {
        int beg = rowptr[v], end = rowptr[v + 1];
        float sd_h = sd[v * 4 + hd];
        int i0 = beg + half * 16;
        for (; i0 + 16 <= end; i0 += 32) {
            int myidx = csr[i0 + sub];
            float sc = ss[myidx * 4 + hd] + sd_h;
            sc = fmaxf(sc, 0.2f * sc);
            float w_reg = __expf(sc);
            unsigned hv[16];
            #pragma unroll
            for (int j = 0; j < 16; ++j) {
                int s = __shfl(myidx, j);
                hv[j] = *(const unsigned*)&h2[s * 64 + lane];
            }
            #pragma unroll
            for (int j = 0; j < 16; ++j) {
                float w = __shfl(w_reg, hd16 + j);
                float2 f = __half22float2(*(const __half2*)&hv[j]);
                acc0 = fmaf(w, f.x, acc0);
                acc1 = fmaf(w, f.y, acc1);
                den += w;
            }
        }
        int rem = end - i0;
        if (rem > 0) {       // rem < 16 by loop exit; lands in exactly one wave
            int myidx = (sub < rem) ? csr[i0 + sub] : -1;
            float w_reg = 0.f;
            if (myidx >= 0) {
                float sc = ss[myidx * 4 + hd] + sd_h;
                sc = fmaxf(sc, 0.2f * sc);
                w_reg = __expf(sc);
            }
            #pragma unroll 4
            for (int j = 0; j < rem; ++j) {
                int s = __shfl(myidx, j);
                float w = __shfl(w_reg, hd16 + j);
                float2 f = __half22float2(h2[s * 64 + lane]);
                acc0 = fmaf(w, f.x, acc0);
                acc1 = fmaf(w, f.y, acc1);
                den += w;
            }
        }
    }
    r0s[wid][lane] = acc0; r1s[wid][lane] = acc1; rds[wid][lane] = den;
    __syncthreads();
    if (half == 0 && valid) {
        acc0 += r0s[wid + 1][lane];
        acc1 += r1s[wid + 1][lane];
        den  += rds[wid + 1][lane];
        float inv = 1.f / den;
        float2 b2 = ((const float2*)bias)[lane];
        float o0 = fmaxf(fmaf(acc0, inv, b2.x), 0.f);
        float o1 = fmaxf(fmaf(acc1, inv, b2.y), 0.f);
        __half2 ov = __floats2half2_rn(o0, o1);
        __builtin_nontemporal_store(*(unsigned int*)&ov,
                                    (unsigned int*)&out[v * 128 + 2 * lane]);
    }
}

// ---- fused alpha + gather, layer 4: 2 waves per node (one per branch) ----
__global__ __launch_bounds__(256) void gather64_both(
        const __half* __restrict__ h0, const __half* __restrict__ h1,
        const float* __restrict__ ss0, const float* __restrict__ ss1,
        const float* __restrict__ sd0, const float* __restrict__ sd1,
        const int* __restrict__ rp0, const int* __restrict__ rp1,
        const int* __restrict__ csr0, const int* __restrict__ csr1,
        const float* __restrict__ bias0, const float* __restrict__ bias1,
        float* __restrict__ out, int n) {
    __shared__ float rsg[4][64];
    int wid = threadIdx.x >> 6, lane = threadIdx.x & 63;
    int pair = wid >> 1, br = wid & 1;
    int v = blockIdx.x * 2 + pair;
    bool valid = (v < n);
    int sub = lane & 15;

    float sg = 0.f;
    if (valid) {
        const __half* h   = br ? h1 : h0;
        const float* ss   = br ? ss1 : ss0;
        const float* sd   = br ? sd1 : sd0;
        const int* rowptr = br ? rp1 : rp0;
        const int* csr    = br ? csr1 : csr0;
        const float* bias = br ? bias1 : bias0;
        int beg = rowptr[v], end = rowptr[v + 1];
        float sd_v = sd[v];
        float acc = 0.f, den = 0.f;
        int i0 = beg;
        for (; i0 + 16 <= end; i0 += 16) {
            int myidx = csr[i0 + sub];
            float sc = ss[myidx] + sd_v;
            sc = fmaxf(sc, 0.2f * sc);
            float w_reg = __expf(sc);
            unsigned short hv[16];
            #pragma unroll
            for (int j = 0; j < 16; ++j) {
                int s = __shfl(myidx, j);
                hv[j] = *(const unsigned short*)&h[s * 64 + lane];
            }
            #pragma unroll
            for (int j = 0; j < 16; ++j) {
                float w = __shfl(w_reg, j);
                float f = __half2float(*(const __half*)&hv[j]);
                acc = fmaf(w, f, acc);
                den += w;
            }
        }
        int rem = end - i0;
        if (rem > 0) {
            int myidx = (sub < rem) ? csr[i0 + sub] : -1;
            float w_reg = 0.f;
            if (myidx >= 0) {
                float sc = ss[myidx] + sd_v;
                sc = fmaxf(sc, 0.2f * sc);
                w_reg = __expf(sc);
            }
            #pragma unroll 4
            for (int j = 0; j < rem; ++j) {
                int s = __shfl(myidx, j);
                float w = __shfl(w_reg, j);
                float f = __half2float(h[s * 64 + lane]);
                acc = fmaf(w, f, acc);
                den += w;
            }
        }
        float o = acc / den + bias[lane];
        sg = 0.5f / (1.f + __expf(-o));
    }
    rsg[wid][lane] = sg;
    __syncthreads();
    if (br == 0 && valid)
        out[(size_t)v * 64 + lane] = sg + rsg[wid + 1][lane];
}

extern "C" void kernel_launch(void* const* d_in, const int* in_sizes, int n_in,
                              void* d_out, int out_size, void* d_ws, size_t ws_size,
                              hipStream_t stream) {
    const int N = in_sizes[0] / 128;      // 20000
    const int E = in_sizes[1] / 2;        // 320000
    const int TOT = E + N;                // edges incl. self loops
    const int NP = N + 4;                 // rowptr stride
    const int NBUK = (N + 63) >> 6;       // 313 buckets of 64 nodes
    const int NBLK = 256;                 // count/scatter blocks per branch

    const float* x1 = (const float*)d_in[0];
    const int*   ei1 = (const int*)d_in[1];
    const float* x2 = (const float*)d_in[2];
    const int*   ei2 = (const int*)d_in[3];
    void* const* P0 = d_in + 4;
    void* const* P1 = d_in + 20;

    // workspace layout (8B-aligned chunks)
    char* w = (char*)d_ws;
    f16* bufX = (f16*)w;               w += (size_t)2 * N * 128 * 2;
    f16* bufH = (f16*)w;               w += (size_t)2 * N * 128 * 2;
    float* s_src = (float*)w;          w += (size_t)2 * N * 4 * 4;
    float* s_dst = (float*)w;          w += (size_t)2 * N * 4 * 4;
    int* rowptr = (int*)w;             w += (size_t)2 * NP * 4;
    int* csr_src = (int*)w;            w += (size_t)2 * TOT * 4;
    int* carr = (int*)w;               w += (size_t)2 * NBLK * NBKP * 4;
    int* btot = (int*)w;               w += (size_t)2 * NBKP * 4;
    int* bbase = (int*)w;              w += (size_t)2 * (NBUK + 1) * 4 + 8;
    long long* pbuf = (long long*)w;   w += (size_t)2 * TOT * 8;
    f16* wsd = (f16*)w;                w += (size_t)8 * 2048 * 2;

    dim3 blk(256);
    int gPair = (N + 1) / 2;              // 2-waves-per-node kernels

    // ---- all score-weight tiles (weights-only dependency) ---------------
    WsdArgs wa;
    for (int l = 0; l < 4; ++l) {
        int o = (l < 3) ? l * 4 : 12;
        wa.W[l * 2 + 0]  = (const float*)P0[o + 0];
        wa.W[l * 2 + 1]  = (const float*)P1[o + 0];
        wa.as[l * 2 + 0] = (const float*)P0[o + 1];
        wa.as[l * 2 + 1] = (const float*)P1[o + 1];
        wa.ad[l * 2 + 0] = (const float*)P0[o + 2];
        wa.ad[l * 2 + 1] = (const float*)P1[o + 2];
    }
    wsd_all<<<dim3(8, 2, 4), blk, 0, stream>>>(wa, wsd);

    // ---- CSR build: bucketed counting sort, no global atomics -----------
    bucket_count<<<dim3(NBLK, 2), blk, 0, stream>>>(ei1, ei2, carr, NBUK, E, TOT);
    bucket_scan1<<<dim3(NBUK, 2), blk, 0, stream>>>(carr, btot, NBLK);
    bucket_scan2<<<dim3(1, 2), dim3(512), 0, stream>>>(btot, bbase, NBUK);
    bucket_scatter<<<dim3(NBLK, 2), blk, 0, stream>>>(ei1, ei2, carr, bbase,
                                                      pbuf, NBUK, E, TOT);
    bucket_finalize<<<dim3(NBUK, 2), blk, 0, stream>>>(pbuf, bbase, rowptr,
                                                       csr_src, N, NBUK, TOT, NP);

    // ---- layers 1..3 (128 -> 4x32, relu), gathers per-branch ------------
    for (int l = 0; l < 3; ++l) {
        if (l == 0)
            gemm_mfma<float><<<dim3(128, 2, 2), blk, 0, stream>>>(
                x1, x2,
                (const float*)P0[0], (const float*)P1[0],
                wsd + (size_t)l * 4096, bufH, s_src, s_dst, N, 128, 4);
        else
            gemm_mfma<f16><<<dim3(128, 2, 2), blk, 0, stream>>>(
                bufX, bufX + (size_t)N * 128,
                (const float*)P0[l*4+0], (const float*)P1[l*4+0],
                wsd + (size_t)l * 4096, bufH, s_src, s_dst, N, 128, 4);
        for (int b = 0; b < 2; ++b)
            gather128_f<<<gPair, blk, 0, stream>>>(
                (const __half2*)(bufH + (size_t)b * N * 128),
                s_src + (size_t)b * N * 4, s_dst + (size_t)b * N * 4,
                rowptr + (size_t)b * NP, csr_src + (size_t)b * TOT,
                (const float*)(b ? P1[l*4+3] : P0[l*4+3]),
                bufX + (size_t)b * N * 128, N);
    }

    // ---- layer 4 (128 -> 1x64, sigmoid, both branches -> d_out) ---------
    gemm_mfma<f16><<<dim3(128, 1, 2), blk, 0, stream>>>(
        bufX, bufX + (size_t)N * 128,
        (const float*)P0[12], (const float*)P1[12],
        wsd + (size_t)3 * 4096, bufH, s_src, s_dst, N, 64, 1);
    gather64_both<<<gPair, blk, 0, stream>>>(
        (const __half*)bufH, (const __half*)(bufH + (size_t)N * 128),
        s_src, s_src + (size_t)N * 4, s_dst, s_dst + (size_t)N * 4,
        rowptr, rowptr + NP, csr_src, csr_src + (size_t)TOT,
        (const float*)P0[15], (const float*)P1[15],
        (float*)d_out, N);
}

// Round 16
// 236.789 us; speedup vs baseline: 1.2130x; 1.2130x over previous
//
#include <hip/hip_runtime.h>
#include <hip/hip_fp16.h>
#include <math.h>

// ---------------------------------------------------------------------------
// dual GAT (2 branches x 4 GATConv layers), N=20000 nodes, E=320000 edges.
// R15 = exact R10 (all R11-R14 gather restructures reverted — each regressed;
// R10's two-phase 16-burst one-wave-per-node gather is the local optimum)
// with ONE mechanical change:
//  - 16-bit CSR: (dst,src) packed into one uint in pbuf (8->4 B/edge),
//    csr_src stored as ushort (4->2 B/edge). Halves CSR-build traffic and
//    gather index-read footprint. Valid since N=20000 < 65536.
// ---------------------------------------------------------------------------

#define WAVE 64
#define NBKP 320   // padded bucket count (N/64 = 313 actual)

typedef _Float16 f16;
typedef f16 f16x8 __attribute__((ext_vector_type(8)));
typedef f16 f16x4 __attribute__((ext_vector_type(4)));
typedef float f32x4 __attribute__((ext_vector_type(4)));

// ---- stage 1: per-(block,bucket) counts (LDS hist, no global atomics) ----
__global__ __launch_bounds__(256) void bucket_count(
        const int* __restrict__ ei0, const int* __restrict__ ei1,
        int* __restrict__ carr, int nbuk, int E, int tot) {
    __shared__ int h[NBKP];
    int br = blockIdx.y;
    const int* ei = br ? ei1 : ei0;
    for (int i = threadIdx.x; i < NBKP; i += 256) h[i] = 0;
    __syncthreads();
    for (int t = blockIdx.x * 256 + threadIdx.x; t < tot; t += 256 * 256) {
        int dst = (t < E) ? ei[E + t] : (t - E);
        atomicAdd(&h[dst >> 6], 1);
    }
    __syncthreads();
    int* c = carr + ((size_t)br * gridDim.x + blockIdx.x) * NBKP;
    for (int i = threadIdx.x; i < NBKP; i += 256) c[i] = h[i];
}

// ---- stage 2a: per-bucket exclusive prefix over the 256 blocks -----------
__global__ __launch_bounds__(256) void bucket_scan1(
        int* __restrict__ carr, int* __restrict__ btot, int nblk) {
    __shared__ int smem[256];
    int br = blockIdx.y, k = blockIdx.x;
    size_t idx = ((size_t)br * nblk + threadIdx.x) * NBKP + k;
    int v = carr[idx];
    smem[threadIdx.x] = v;
    __syncthreads();
    #pragma unroll
    for (int off = 1; off < 256; off <<= 1) {
        int t = (threadIdx.x >= off) ? smem[threadIdx.x - off] : 0;
        __syncthreads();
        smem[threadIdx.x] += t;
        __syncthreads();
    }
    carr[idx] = smem[threadIdx.x] - v;            // exclusive prefix
    if (threadIdx.x == 255) btot[br * NBKP + k] = smem[255];
}

// ---- stage 2b: bucket bases (512-thread LDS scan over bucket totals) -----
__global__ __launch_bounds__(512) void bucket_scan2(
        const int* __restrict__ btot, int* __restrict__ bbase, int nbuk) {
    __shared__ int smem[512];
    int br = blockIdx.y;
    int v = (threadIdx.x < nbuk) ? btot[br * NBKP + threadIdx.x] : 0;
    smem[threadIdx.x] = v;
    __syncthreads();
    #pragma unroll
    for (int off = 1; off < 512; off <<= 1) {
        int t = (threadIdx.x >= off) ? smem[threadIdx.x - off] : 0;
        __syncthreads();
        smem[threadIdx.x] += t;
        __syncthreads();
    }
    int* bb = bbase + br * (nbuk + 1);
    if (threadIdx.x < nbuk) bb[threadIdx.x] = smem[threadIdx.x] - v;
    if (threadIdx.x == nbuk - 1) bb[nbuk] = smem[threadIdx.x];
}

// ---- stage 3: deterministic-slot pair scatter (uint-packed dst|src) ------
__global__ __launch_bounds__(256) void bucket_scatter(
        const int* __restrict__ ei0, const int* __restrict__ ei1,
        const int* __restrict__ carr, const int* __restrict__ bbase,
        unsigned int* __restrict__ pbuf, int nbuk, int E, int tot) {
    __shared__ int base_s[NBKP];
    __shared__ int h[NBKP];
    int br = blockIdx.y;
    const int* ei = br ? ei1 : ei0;
    const int* offb = carr + ((size_t)br * gridDim.x + blockIdx.x) * NBKP;
    const int* bb = bbase + br * (nbuk + 1);
    unsigned int* pb = pbuf + (size_t)br * tot;
    for (int i = threadIdx.x; i < NBKP; i += 256) {
        h[i] = 0;
        base_s[i] = (i < nbuk) ? (bb[i] + offb[i]) : 0;
    }
    __syncthreads();
    for (int t = blockIdx.x * 256 + threadIdx.x; t < tot; t += 256 * 256) {
        int src, dst;
        if (t < E) { src = ei[t]; dst = ei[E + t]; }
        else       { src = dst = t - E; }
        int k = dst >> 6;
        int r = atomicAdd(&h[k], 1);        // LDS rank
        pb[base_s[k] + r] = ((unsigned)dst << 16) | (unsigned)src;
    }
}

// ---- stage 4: per-bucket exact CSR (ushort src) + rowptr -----------------
__global__ __launch_bounds__(256) void bucket_finalize(
        const unsigned int* __restrict__ pbuf, const int* __restrict__ bbase,
        int* __restrict__ rowptrb, unsigned short* __restrict__ csrb,
        int n, int nbuk, int tot, int np) {
    __shared__ int h64[64], excl[64], cur[64];
    int br = blockIdx.y, k = blockIdx.x;
    const int* bb = bbase + br * (nbuk + 1);
    const unsigned int* pb = pbuf + (size_t)br * tot;
    int base = bb[k], endb = bb[k + 1], cnt = endb - base;
    int* rp = rowptrb + (size_t)br * np;
    unsigned short* cs = csrb + (size_t)br * tot;
    int d0 = k << 6;
    int nn = min(64, n - d0);
    if (threadIdx.x < 64) h64[threadIdx.x] = 0;
    __syncthreads();
    for (int i = threadIdx.x; i < cnt; i += 256) {
        int dst = (int)(pb[base + i] >> 16);
        atomicAdd(&h64[dst & 63], 1);
    }
    __syncthreads();
    if (threadIdx.x == 0) {
        int run = 0;
        for (int j = 0; j < 64; ++j) { excl[j] = run; run += h64[j]; }
    }
    __syncthreads();
    if (threadIdx.x < 64) cur[threadIdx.x] = excl[threadIdx.x];
    if (threadIdx.x < nn) rp[d0 + threadIdx.x] = base + excl[threadIdx.x];
    if (k == nbuk - 1 && threadIdx.x == 64) rp[n] = endb;
    __syncthreads();
    for (int i = threadIdx.x; i < cnt; i += 256) {
        unsigned int p = pb[base + i];
        int dst = (int)(p >> 16);
        unsigned short src = (unsigned short)(p & 0xFFFFu);
        int slot = atomicAdd(&cur[dst & 63], 1);
        cs[base + slot] = src;
    }
}

// ---- score-weight tiles for ALL layers in one launch ---------------------
struct WsdArgs {
    const float* W[8];    // [layer*2+branch]
    const float* as[8];
    const float* ad[8];
};

__global__ __launch_bounds__(256) void wsd_all(WsdArgs a, f16* __restrict__ wsd) {
    int l = blockIdx.z, b = blockIdx.y;
    int fout = (l == 3) ? 64 : 128;
    int H    = (l == 3) ? 1 : 4;
    int C    = (l == 3) ? 64 : 32;
    const float* W   = a.W[l * 2 + b];
    const float* a_s = a.as[l * 2 + b];
    const float* a_d = a.ad[l * 2 + b];
    f16* out = wsd + ((size_t)(l * 2 + b)) * 16 * 128;
    int k = blockIdx.x * 16 + (threadIdx.x & 15);
    int sc = threadIdx.x >> 4;
    float sum = 0.f;
    if (sc < 2 * H) {
        int hd = (sc < H) ? sc : sc - H;
        const float* av = (sc < H) ? a_s : a_d;
        const float4* Wr = (const float4*)(W + (size_t)k * fout + hd * C);
        const float4* ar = (const float4*)(av + hd * C);
        for (int c = 0; c < (C >> 2); ++c) {
            float4 wv = Wr[c]; float4 a4 = ar[c];
            sum += wv.x * a4.x + wv.y * a4.y + wv.z * a4.z + wv.w * a4.w;
        }
    }
    out[sc * 128 + k] = (f16)sum;
}

// ---- MFMA GEMM: h = x@W (f32 acc, fp16 out) + score cols ----------------
template <typename XT>
__global__ __launch_bounds__(256) void gemm_mfma(
        const XT* __restrict__ x0, const XT* __restrict__ x1,
        const float* __restrict__ W0, const float* __restrict__ W1,
        const f16* __restrict__ wsd,
        f16* __restrict__ hb, float* __restrict__ ssb, float* __restrict__ sdb,
        int n, int fout, int H) {
    __shared__ f16 xl[64 * 136];
    __shared__ f16 wl[80 * 136];
    int b = blockIdx.z;
    const XT* x = b ? x1 : x0;
    const float* W = b ? W1 : W0;
    f16* h = hb + (size_t)b * n * 128;
    float* ss = ssb + (size_t)b * n * 4;
    float* sd = sdb + (size_t)b * n * 4;
    int colbase = blockIdx.y * 64;
    bool last = (blockIdx.y == gridDim.y - 1);
    int lane = threadIdx.x & 63, w = threadIdx.x >> 6;

    {
        int c = threadIdx.x & 63, kb = (threadIdx.x >> 6) * 32;
        #pragma unroll 8
        for (int j = 0; j < 32; ++j)
            wl[c * 136 + kb + j] = (f16)W[(size_t)(kb + j) * fout + colbase + c];
    }
    if (last) {
        int c = threadIdx.x & 15, kb = (threadIdx.x >> 4) * 8;
        *(f16x8*)&wl[(64 + c) * 136 + kb] =
            *(const f16x8*)&wsd[(size_t)b * 2048 + c * 128 + kb];
    }
    __syncthreads();

    f16x8 B[5][4];
    #pragma unroll
    for (int ct = 0; ct < 5; ++ct)
        #pragma unroll
        for (int kc = 0; kc < 4; ++kc)
            B[ct][kc] = *(const f16x8*)
                &wl[(ct * 16 + (lane & 15)) * 136 + kc * 32 + (lane >> 4) * 8];

    for (int base = blockIdx.x * 64; base < n; base += gridDim.x * 64) {
        __syncthreads();
        {
            int r = threadIdx.x >> 2, k0 = (threadIdx.x & 3) * 32;
            int row = base + r;
            if (row < n) {
                if constexpr (sizeof(XT) == 4) {
                    const float4* x4 = (const float4*)x;
                    #pragma unroll
                    for (int j = 0; j < 8; ++j) {
                        float4 v = x4[(size_t)row * 32 + (k0 >> 2) + j];
                        f16x4 hv = {(f16)v.x, (f16)v.y, (f16)v.z, (f16)v.w};
                        *(f16x4*)&xl[r * 136 + k0 + 4 * j] = hv;
                    }
                } else {
                    const f16x8* x8 = (const f16x8*)x;
                    #pragma unroll
                    for (int j = 0; j < 4; ++j)
                        *(f16x8*)&xl[r * 136 + k0 + 8 * j] =
                            x8[(size_t)row * 16 + (k0 >> 3) + j];
                }
            } else {
                f16x4 z = {(f16)0.f, (f16)0.f, (f16)0.f, (f16)0.f};
                #pragma unroll
                for (int j = 0; j < 8; ++j)
                    *(f16x4*)&xl[r * 136 + k0 + 4 * j] = z;
            }
        }
        __syncthreads();

        f16x8 A[4];
        #pragma unroll
        for (int kc = 0; kc < 4; ++kc)
            A[kc] = *(const f16x8*)
                &xl[(w * 16 + (lane & 15)) * 136 + kc * 32 + (lane >> 4) * 8];

        f32x4 acc[5];
        #pragma unroll
        for (int ct = 0; ct < 5; ++ct) acc[ct] = (f32x4){0.f, 0.f, 0.f, 0.f};
        #pragma unroll
        for (int ct = 0; ct < 5; ++ct)
            #pragma unroll
            for (int kc = 0; kc < 4; ++kc)
                acc[ct] = __builtin_amdgcn_mfma_f32_16x16x32_f16(
                    A[kc], B[ct][kc], acc[ct], 0, 0, 0);

        int r0 = base + w * 16 + (lane >> 4) * 4;
        int c0 = lane & 15;
        #pragma unroll
        for (int ct = 0; ct < 4; ++ct) {
            int col = colbase + ct * 16 + c0;
            #pragma unroll
            for (int j = 0; j < 4; ++j) {
                int row = r0 + j;
                if (row < n) h[(size_t)row * fout + col] = (f16)acc[ct][j];
            }
        }
        if (last) {
            #pragma unroll
            for (int j = 0; j < 4; ++j) {
                int row = r0 + j;
                if (row < n) {
                    float v = acc[4][j];
                    if (c0 < H)          ss[(size_t)row * H + c0] = v;
                    else if (c0 < 2 * H) sd[(size_t)row * H + c0 - H] = v;
                }
            }
        }
    }
}

// ---- fused alpha + gather, 128-wide layers (4 heads x 32) ---------------
// R10 loop body: two-phase chunks (16 loads in flight), one wave per node.
__global__ __launch_bounds__(256) void gather128_f(
        const __half2* __restrict__ h2, const float* __restrict__ ss,
        const float* __restrict__ sd, const int* __restrict__ rowptr,
        const unsigned short* __restrict__ csr, const float* __restrict__ bias,
        f16* __restrict__ out, int n) {
    int wid = threadIdx.x >> 6, lane = threadIdx.x & 63;
    int v = blockIdx.x * 4 + wid;
    if (v >= n) return;
    int beg = rowptr[v], end = rowptr[v + 1];
    int hd = lane >> 4;
    int sub = lane & 15;
    int hd16 = hd * 16;
    float sd_h = sd[v * 4 + hd];

    float acc0 = 0.f, acc1 = 0.f, den = 0.f;
    int i0 = beg;
    for (; i0 + 16 <= end; i0 += 16) {
        int myidx = csr[i0 + sub];
        float sc = ss[myidx * 4 + hd] + sd_h;
        sc = fmaxf(sc, 0.2f * sc);
        float w_reg = __expf(sc);
        unsigned hv[16];
        #pragma unroll
        for (int j = 0; j < 16; ++j) {
            int s = __shfl(myidx, j);
            hv[j] = *(const unsigned*)&h2[s * 64 + lane];
        }
        #pragma unroll
        for (int j = 0; j < 16; ++j) {
            float w = __shfl(w_reg, hd16 + j);
            float2 f = __half22float2(*(const __half2*)&hv[j]);
            acc0 = fmaf(w, f.x, acc0);
            acc1 = fmaf(w, f.y, acc1);
            den += w;
        }
    }
    int rem = end - i0;
    if (rem > 0) {
        int myidx = (sub < rem) ? (int)csr[i0 + sub] : -1;
        float w_reg = 0.f;
        if (myidx >= 0) {
            float sc = ss[myidx * 4 + hd] + sd_h;
            sc = fmaxf(sc, 0.2f * sc);
            w_reg = __expf(sc);
        }
        #pragma unroll 4
        for (int j = 0; j < rem; ++j) {
            int s = __shfl(myidx, j);
            float w = __shfl(w_reg, hd16 + j);
            float2 f = __half22float2(h2[s * 64 + lane]);
            acc0 = fmaf(w, f.x, acc0);
            acc1 = fmaf(w, f.y, acc1);
            den += w;
        }
    }

    float inv = 1.f / den;
    float2 b2 = ((const float2*)bias)[lane];
    float o0 = fmaxf(fmaf(acc0, inv, b2.x), 0.f);
    float o1 = fmaxf(fmaf(acc1, inv, b2.y), 0.f);
    __half2 ov = __floats2half2_rn(o0, o1);
    __builtin_nontemporal_store(*(unsigned int*)&ov,
                                (unsigned int*)&out[v * 128 + 2 * lane]);
}

// ---- fused alpha + gather, layer 4, BOTH branches -> single d_out write --
__global__ __launch_bounds__(256) void gather64_both(
        const __half* __restrict__ h0, const __half* __restrict__ h1,
        const float* __restrict__ ss0, const float* __restrict__ ss1,
        const float* __restrict__ sd0, const float* __restrict__ sd1,
        const int* __restrict__ rp0, const int* __restrict__ rp1,
        const unsigned short* __restrict__ csr0,
        const unsigned short* __restrict__ csr1,
        const float* __restrict__ bias0, const float* __restrict__ bias1,
        float* __restrict__ out, int n) {
    int wid = threadIdx.x >> 6, lane = threadIdx.x & 63;
    int v = blockIdx.x * 4 + wid;
    if (v >= n) return;
    int sub = lane & 15;
    float og = 0.f;

    #pragma unroll
    for (int br = 0; br < 2; ++br) {
        const __half* h   = br ? h1 : h0;
        const float* ss   = br ? ss1 : ss0;
        const float* sd   = br ? sd1 : sd0;
        const int* rowptr = br ? rp1 : rp0;
        const unsigned short* csr = br ? csr1 : csr0;
        const float* bias = br ? bias1 : bias0;
        int beg = rowptr[v], end = rowptr[v + 1];
        float sd_v = sd[v];
        float acc = 0.f, den = 0.f;
        int i0 = beg;
        for (; i0 + 16 <= end; i0 += 16) {
            int myidx = csr[i0 + sub];
            float sc = ss[myidx] + sd_v;
            sc = fmaxf(sc, 0.2f * sc);
            float w_reg = __expf(sc);
            unsigned short hv[16];
            #pragma unroll
            for (int j = 0; j < 16; ++j) {
                int s = __shfl(myidx, j);
                hv[j] = *(const unsigned short*)&h[s * 64 + lane];
            }
            #pragma unroll
            for (int j = 0; j < 16; ++j) {
                float w = __shfl(w_reg, j);
                float f = __half2float(*(const __half*)&hv[j]);
                acc = fmaf(w, f, acc);
                den += w;
            }
        }
        int rem = end - i0;
        if (rem > 0) {
            int myidx = (sub < rem) ? (int)csr[i0 + sub] : -1;
            float w_reg = 0.f;
            if (myidx >= 0) {
                float sc = ss[myidx] + sd_v;
                sc = fmaxf(sc, 0.2f * sc);
                w_reg = __expf(sc);
            }
            #pragma unroll 4
            for (int j = 0; j < rem; ++j) {
                int s = __shfl(myidx, j);
                float w = __shfl(w_reg, j);
                float f = __half2float(h[s * 64 + lane]);
                acc = fmaf(w, f, acc);
                den += w;
            }
        }
        float o = acc / den + bias[lane];
        og += 0.5f / (1.f + __expf(-o));
    }
    out[(size_t)v * 64 + lane] = og;
}

extern "C" void kernel_launch(void* const* d_in, const int* in_sizes, int n_in,
                              void* d_out, int out_size, void* d_ws, size_t ws_size,
                              hipStream_t stream) {
    const int N = in_sizes[0] / 128;      // 20000
    const int E = in_sizes[1] / 2;        // 320000
    const int TOT = E + N;                // edges incl. self loops
    const int NP = N + 4;                 // rowptr stride
    const int NBUK = (N + 63) >> 6;       // 313 buckets of 64 nodes
    const int NBLK = 256;                 // count/scatter blocks per branch

    const float* x1 = (const float*)d_in[0];
    const int*   ei1 = (const int*)d_in[1];
    const float* x2 = (const float*)d_in[2];
    const int*   ei2 = (const int*)d_in[3];
    void* const* P0 = d_in + 4;
    void* const* P1 = d_in + 20;

    // workspace layout (8B-aligned chunks)
    char* w = (char*)d_ws;
    f16* bufX = (f16*)w;                 w += (size_t)2 * N * 128 * 2;
    f16* bufH = (f16*)w;                 w += (size_t)2 * N * 128 * 2;
    float* s_src = (float*)w;            w += (size_t)2 * N * 4 * 4;
    float* s_dst = (float*)w;            w += (size_t)2 * N * 4 * 4;
    int* rowptr = (int*)w;               w += (size_t)2 * NP * 4;
    unsigned short* csr_src = (unsigned short*)w;  w += (size_t)2 * TOT * 2 + 4;
    int* carr = (int*)w;                 w += (size_t)2 * NBLK * NBKP * 4;
    int* btot = (int*)w;                 w += (size_t)2 * NBKP * 4;
    int* bbase = (int*)w;                w += (size_t)2 * (NBUK + 1) * 4 + 8;
    unsigned int* pbuf = (unsigned int*)w;  w += (size_t)2 * TOT * 4;
    f16* wsd = (f16*)w;                  w += (size_t)8 * 2048 * 2;

    dim3 blk(256);
    int gWave  = (N + 3) / 4;             // wave-per-node kernels

    // ---- all score-weight tiles (weights-only dependency) ---------------
    WsdArgs wa;
    for (int l = 0; l < 4; ++l) {
        int o = (l < 3) ? l * 4 : 12;
        wa.W[l * 2 + 0]  = (const float*)P0[o + 0];
        wa.W[l * 2 + 1]  = (const float*)P1[o + 0];
        wa.as[l * 2 + 0] = (const float*)P0[o + 1];
        wa.as[l * 2 + 1] = (const float*)P1[o + 1];
        wa.ad[l * 2 + 0] = (const float*)P0[o + 2];
        wa.ad[l * 2 + 1] = (const float*)P1[o + 2];
    }
    wsd_all<<<dim3(8, 2, 4), blk, 0, stream>>>(wa, wsd);

    // ---- CSR build: bucketed counting sort, no global atomics -----------
    bucket_count<<<dim3(NBLK, 2), blk, 0, stream>>>(ei1, ei2, carr, NBUK, E, TOT);
    bucket_scan1<<<dim3(NBUK, 2), blk, 0, stream>>>(carr, btot, NBLK);
    bucket_scan2<<<dim3(1, 2), dim3(512), 0, stream>>>(btot, bbase, NBUK);
    bucket_scatter<<<dim3(NBLK, 2), blk, 0, stream>>>(ei1, ei2, carr, bbase,
                                                      pbuf, NBUK, E, TOT);
    bucket_finalize<<<dim3(NBUK, 2), blk, 0, stream>>>(pbuf, bbase, rowptr,
                                                       csr_src, N, NBUK, TOT, NP);

    // ---- layers 1..3 (128 -> 4x32, relu), gathers per-branch ------------
    for (int l = 0; l < 3; ++l) {
        if (l == 0)
            gemm_mfma<float><<<dim3(128, 2, 2), blk, 0, stream>>>(
                x1, x2,
                (const float*)P0[0], (const float*)P1[0],
                wsd + (size_t)l * 4096, bufH, s_src, s_dst, N, 128, 4);
        else
            gemm_mfma<f16><<<dim3(128, 2, 2), blk, 0, stream>>>(
                bufX, bufX + (size_t)N * 128,
                (const float*)P0[l*4+0], (const float*)P1[l*4+0],
                wsd + (size_t)l * 4096, bufH, s_src, s_dst, N, 128, 4);
        for (int b = 0; b < 2; ++b)
            gather128_f<<<gWave, blk, 0, stream>>>(
                (const __half2*)(bufH + (size_t)b * N * 128),
                s_src + (size_t)b * N * 4, s_dst + (size_t)b * N * 4,
                rowptr + (size_t)b * NP, csr_src + (size_t)b * TOT,
                (const float*)(b ? P1[l*4+3] : P0[l*4+3]),
                bufX + (size_t)b * N * 128, N);
    }

    // ---- layer 4 (128 -> 1x64, sigmoid, both branches -> d_out) ---------
    gemm_mfma<f16><<<dim3(128, 1, 2), blk, 0, stream>>>(
        bufX, bufX + (size_t)N * 128,
        (const float*)P0[12], (const float*)P1[12],
        wsd + (size_t)3 * 4096, bufH, s_src, s_dst, N, 64, 1);
    gather64_both<<<gWave, blk, 0, stream>>>(
        (const __half*)bufH, (const __half*)(bufH + (size_t)N * 128),
        s_src, s_src + (size_t)N * 4, s_dst, s_dst + (size_t)N * 4,
        rowptr, rowptr + NP, csr_src, csr_src + (size_t)TOT,
        (const float*)P0[15], (const float*)P1[15],
        (float*)d_out, N);
}

// Round 17
// 235.714 us; speedup vs baseline: 1.2185x; 1.0046x over previous
//
#include <hip/hip_runtime.h>
#include <hip/hip_fp16.h>
#include <math.h>

// ---------------------------------------------------------------------------
// dual GAT (2 branches x 4 GATConv layers), N=20000 nodes, E=320000 edges.
// R16 = R15 (best: 236.8us) with two minimal tweaks:
//  - gather128_f writes bufX with PLAIN stores (was nontemporal): bufX is
//    read by the next gemm -- keep it L2-warm.
//  - chunk loop: score gather+exp moved AFTER the 16 h-load issues (overlap
//    score latency under h loads; for-loop shape unchanged).
// ---------------------------------------------------------------------------

#define WAVE 64
#define NBKP 320   // padded bucket count (N/64 = 313 actual)

typedef _Float16 f16;
typedef f16 f16x8 __attribute__((ext_vector_type(8)));
typedef f16 f16x4 __attribute__((ext_vector_type(4)));
typedef float f32x4 __attribute__((ext_vector_type(4)));

// ---- stage 1: per-(block,bucket) counts (LDS hist, no global atomics) ----
__global__ __launch_bounds__(256) void bucket_count(
        const int* __restrict__ ei0, const int* __restrict__ ei1,
        int* __restrict__ carr, int nbuk, int E, int tot) {
    __shared__ int h[NBKP];
    int br = blockIdx.y;
    const int* ei = br ? ei1 : ei0;
    for (int i = threadIdx.x; i < NBKP; i += 256) h[i] = 0;
    __syncthreads();
    for (int t = blockIdx.x * 256 + threadIdx.x; t < tot; t += 256 * 256) {
        int dst = (t < E) ? ei[E + t] : (t - E);
        atomicAdd(&h[dst >> 6], 1);
    }
    __syncthreads();
    int* c = carr + ((size_t)br * gridDim.x + blockIdx.x) * NBKP;
    for (int i = threadIdx.x; i < NBKP; i += 256) c[i] = h[i];
}

// ---- stage 2a: per-bucket exclusive prefix over the 256 blocks -----------
__global__ __launch_bounds__(256) void bucket_scan1(
        int* __restrict__ carr, int* __restrict__ btot, int nblk) {
    __shared__ int smem[256];
    int br = blockIdx.y, k = blockIdx.x;
    size_t idx = ((size_t)br * nblk + threadIdx.x) * NBKP + k;
    int v = carr[idx];
    smem[threadIdx.x] = v;
    __syncthreads();
    #pragma unroll
    for (int off = 1; off < 256; off <<= 1) {
        int t = (threadIdx.x >= off) ? smem[threadIdx.x - off] : 0;
        __syncthreads();
        smem[threadIdx.x] += t;
        __syncthreads();
    }
    carr[idx] = smem[threadIdx.x] - v;            // exclusive prefix
    if (threadIdx.x == 255) btot[br * NBKP + k] = smem[255];
}

// ---- stage 2b: bucket bases (512-thread LDS scan over bucket totals) -----
__global__ __launch_bounds__(512) void bucket_scan2(
        const int* __restrict__ btot, int* __restrict__ bbase, int nbuk) {
    __shared__ int smem[512];
    int br = blockIdx.y;
    int v = (threadIdx.x < nbuk) ? btot[br * NBKP + threadIdx.x] : 0;
    smem[threadIdx.x] = v;
    __syncthreads();
    #pragma unroll
    for (int off = 1; off < 512; off <<= 1) {
        int t = (threadIdx.x >= off) ? smem[threadIdx.x - off] : 0;
        __syncthreads();
        smem[threadIdx.x] += t;
        __syncthreads();
    }
    int* bb = bbase + br * (nbuk + 1);
    if (threadIdx.x < nbuk) bb[threadIdx.x] = smem[threadIdx.x] - v;
    if (threadIdx.x == nbuk - 1) bb[nbuk] = smem[threadIdx.x];
}

// ---- stage 3: deterministic-slot pair scatter (uint-packed dst|src) ------
__global__ __launch_bounds__(256) void bucket_scatter(
        const int* __restrict__ ei0, const int* __restrict__ ei1,
        const int* __restrict__ carr, const int* __restrict__ bbase,
        unsigned int* __restrict__ pbuf, int nbuk, int E, int tot) {
    __shared__ int base_s[NBKP];
    __shared__ int h[NBKP];
    int br = blockIdx.y;
    const int* ei = br ? ei1 : ei0;
    const int* offb = carr + ((size_t)br * gridDim.x + blockIdx.x) * NBKP;
    const int* bb = bbase + br * (nbuk + 1);
    unsigned int* pb = pbuf + (size_t)br * tot;
    for (int i = threadIdx.x; i < NBKP; i += 256) {
        h[i] = 0;
        base_s[i] = (i < nbuk) ? (bb[i] + offb[i]) : 0;
    }
    __syncthreads();
    for (int t = blockIdx.x * 256 + threadIdx.x; t < tot; t += 256 * 256) {
        int src, dst;
        if (t < E) { src = ei[t]; dst = ei[E + t]; }
        else       { src = dst = t - E; }
        int k = dst >> 6;
        int r = atomicAdd(&h[k], 1);        // LDS rank
        pb[base_s[k] + r] = ((unsigned)dst << 16) | (unsigned)src;
    }
}

// ---- stage 4: per-bucket exact CSR (ushort src) + rowptr -----------------
__global__ __launch_bounds__(256) void bucket_finalize(
        const unsigned int* __restrict__ pbuf, const int* __restrict__ bbase,
        int* __restrict__ rowptrb, unsigned short* __restrict__ csrb,
        int n, int nbuk, int tot, int np) {
    __shared__ int h64[64], excl[64], cur[64];
    int br = blockIdx.y, k = blockIdx.x;
    const int* bb = bbase + br * (nbuk + 1);
    const unsigned int* pb = pbuf + (size_t)br * tot;
    int base = bb[k], endb = bb[k + 1], cnt = endb - base;
    int* rp = rowptrb + (size_t)br * np;
    unsigned short* cs = csrb + (size_t)br * tot;
    int d0 = k << 6;
    int nn = min(64, n - d0);
    if (threadIdx.x < 64) h64[threadIdx.x] = 0;
    __syncthreads();
    for (int i = threadIdx.x; i < cnt; i += 256) {
        int dst = (int)(pb[base + i] >> 16);
        atomicAdd(&h64[dst & 63], 1);
    }
    __syncthreads();
    if (threadIdx.x == 0) {
        int run = 0;
        for (int j = 0; j < 64; ++j) { excl[j] = run; run += h64[j]; }
    }
    __syncthreads();
    if (threadIdx.x < 64) cur[threadIdx.x] = excl[threadIdx.x];
    if (threadIdx.x < nn) rp[d0 + threadIdx.x] = base + excl[threadIdx.x];
    if (k == nbuk - 1 && threadIdx.x == 64) rp[n] = endb;
    __syncthreads();
    for (int i = threadIdx.x; i < cnt; i += 256) {
        unsigned int p = pb[base + i];
        int dst = (int)(p >> 16);
        unsigned short src = (unsigned short)(p & 0xFFFFu);
        int slot = atomicAdd(&cur[dst & 63], 1);
        cs[base + slot] = src;
    }
}

// ---- score-weight tiles for ALL layers in one launch ---------------------
struct WsdArgs {
    const float* W[8];    // [layer*2+branch]
    const float* as[8];
    const float* ad[8];
};

__global__ __launch_bounds__(256) void wsd_all(WsdArgs a, f16* __restrict__ wsd) {
    int l = blockIdx.z, b = blockIdx.y;
    int fout = (l == 3) ? 64 : 128;
    int H    = (l == 3) ? 1 : 4;
    int C    = (l == 3) ? 64 : 32;
    const float* W   = a.W[l * 2 + b];
    const float* a_s = a.as[l * 2 + b];
    const float* a_d = a.ad[l * 2 + b];
    f16* out = wsd + ((size_t)(l * 2 + b)) * 16 * 128;
    int k = blockIdx.x * 16 + (threadIdx.x & 15);
    int sc = threadIdx.x >> 4;
    float sum = 0.f;
    if (sc < 2 * H) {
        int hd = (sc < H) ? sc : sc - H;
        const float* av = (sc < H) ? a_s : a_d;
        const float4* Wr = (const float4*)(W + (size_t)k * fout + hd * C);
        const float4* ar = (const float4*)(av + hd * C);
        for (int c = 0; c < (C >> 2); ++c) {
            float4 wv = Wr[c]; float4 a4 = ar[c];
            sum += wv.x * a4.x + wv.y * a4.y + wv.z * a4.z + wv.w * a4.w;
        }
    }
    out[sc * 128 + k] = (f16)sum;
}

// ---- MFMA GEMM: h = x@W (f32 acc, fp16 out) + score cols ----------------
template <typename XT>
__global__ __launch_bounds__(256) void gemm_mfma(
        const XT* __restrict__ x0, const XT* __restrict__ x1,
        const float* __restrict__ W0, const float* __restrict__ W1,
        const f16* __restrict__ wsd,
        f16* __restrict__ hb, float* __restrict__ ssb, float* __restrict__ sdb,
        int n, int fout, int H) {
    __shared__ f16 xl[64 * 136];
    __shared__ f16 wl[80 * 136];
    int b = blockIdx.z;
    const XT* x = b ? x1 : x0;
    const float* W = b ? W1 : W0;
    f16* h = hb + (size_t)b * n * 128;
    float* ss = ssb + (size_t)b * n * 4;
    float* sd = sdb + (size_t)b * n * 4;
    int colbase = blockIdx.y * 64;
    bool last = (blockIdx.y == gridDim.y - 1);
    int lane = threadIdx.x & 63, w = threadIdx.x >> 6;

    {
        int c = threadIdx.x & 63, kb = (threadIdx.x >> 6) * 32;
        #pragma unroll 8
        for (int j = 0; j < 32; ++j)
            wl[c * 136 + kb + j] = (f16)W[(size_t)(kb + j) * fout + colbase + c];
    }
    if (last) {
        int c = threadIdx.x & 15, kb = (threadIdx.x >> 4) * 8;
        *(f16x8*)&wl[(64 + c) * 136 + kb] =
            *(const f16x8*)&wsd[(size_t)b * 2048 + c * 128 + kb];
    }
    __syncthreads();

    f16x8 B[5][4];
    #pragma unroll
    for (int ct = 0; ct < 5; ++ct)
        #pragma unroll
        for (int kc = 0; kc < 4; ++kc)
            B[ct][kc] = *(const f16x8*)
                &wl[(ct * 16 + (lane & 15)) * 136 + kc * 32 + (lane >> 4) * 8];

    for (int base = blockIdx.x * 64; base < n; base += gridDim.x * 64) {
        __syncthreads();
        {
            int r = threadIdx.x >> 2, k0 = (threadIdx.x & 3) * 32;
            int row = base + r;
            if (row < n) {
                if constexpr (sizeof(XT) == 4) {
                    const float4* x4 = (const float4*)x;
                    #pragma unroll
                    for (int j = 0; j < 8; ++j) {
                        float4 v = x4[(size_t)row * 32 + (k0 >> 2) + j];
                        f16x4 hv = {(f16)v.x, (f16)v.y, (f16)v.z, (f16)v.w};
                        *(f16x4*)&xl[r * 136 + k0 + 4 * j] = hv;
                    }
                } else {
                    const f16x8* x8 = (const f16x8*)x;
                    #pragma unroll
                    for (int j = 0; j < 4; ++j)
                        *(f16x8*)&xl[r * 136 + k0 + 8 * j] =
                            x8[(size_t)row * 16 + (k0 >> 3) + j];
                }
            } else {
                f16x4 z = {(f16)0.f, (f16)0.f, (f16)0.f, (f16)0.f};
                #pragma unroll
                for (int j = 0; j < 8; ++j)
                    *(f16x4*)&xl[r * 136 + k0 + 4 * j] = z;
            }
        }
        __syncthreads();

        f16x8 A[4];
        #pragma unroll
        for (int kc = 0; kc < 4; ++kc)
            A[kc] = *(const f16x8*)
                &xl[(w * 16 + (lane & 15)) * 136 + kc * 32 + (lane >> 4) * 8];

        f32x4 acc[5];
        #pragma unroll
        for (int ct = 0; ct < 5; ++ct) acc[ct] = (f32x4){0.f, 0.f, 0.f, 0.f};
        #pragma unroll
        for (int ct = 0; ct < 5; ++ct)
            #pragma unroll
            for (int kc = 0; kc < 4; ++kc)
                acc[ct] = __builtin_amdgcn_mfma_f32_16x16x32_f16(
                    A[kc], B[ct][kc], acc[ct], 0, 0, 0);

        int r0 = base + w * 16 + (lane >> 4) * 4;
        int c0 = lane & 15;
        #pragma unroll
        for (int ct = 0; ct < 4; ++ct) {
            int col = colbase + ct * 16 + c0;
            #pragma unroll
            for (int j = 0; j < 4; ++j) {
                int row = r0 + j;
                if (row < n) h[(size_t)row * fout + col] = (f16)acc[ct][j];
            }
        }
        if (last) {
            #pragma unroll
            for (int j = 0; j < 4; ++j) {
                int row = r0 + j;
                if (row < n) {
                    float v = acc[4][j];
                    if (c0 < H)          ss[(size_t)row * H + c0] = v;
                    else if (c0 < 2 * H) sd[(size_t)row * H + c0 - H] = v;
                }
            }
        }
    }
}

// ---- fused alpha + gather, 128-wide layers (4 heads x 32) ---------------
// two-phase chunks; h-loads issued before the score gather (R16 reorder);
// plain bufX stores (R16: keep L2-warm for next gemm).
__global__ __launch_bounds__(256) void gather128_f(
        const __half2* __restrict__ h2, const float* __restrict__ ss,
        const float* __restrict__ sd, const int* __restrict__ rowptr,
        const unsigned short* __restrict__ csr, const float* __restrict__ bias,
        f16* __restrict__ out, int n) {
    int wid = threadIdx.x >> 6, lane = threadIdx.x & 63;
    int v = blockIdx.x * 4 + wid;
    if (v >= n) return;
    int beg = rowptr[v], end = rowptr[v + 1];
    int hd = lane >> 4;
    int sub = lane & 15;
    int hd16 = hd * 16;
    float sd_h = sd[v * 4 + hd];

    float acc0 = 0.f, acc1 = 0.f, den = 0.f;
    int i0 = beg;
    for (; i0 + 16 <= end; i0 += 16) {
        int myidx = csr[i0 + sub];
        unsigned hv[16];
        #pragma unroll
        for (int j = 0; j < 16; ++j) {
            int s = __shfl(myidx, j);
            hv[j] = *(const unsigned*)&h2[s * 64 + lane];
        }
        // score gather + exp overlapped under the h-load latency
        float sc = ss[myidx * 4 + hd] + sd_h;
        sc = fmaxf(sc, 0.2f * sc);
        float w_reg = __expf(sc);
        #pragma unroll
        for (int j = 0; j < 16; ++j) {
            float w = __shfl(w_reg, hd16 + j);
            float2 f = __half22float2(*(const __half2*)&hv[j]);
            acc0 = fmaf(w, f.x, acc0);
            acc1 = fmaf(w, f.y, acc1);
            den += w;
        }
    }
    int rem = end - i0;
    if (rem > 0) {
        int myidx = (sub < rem) ? (int)csr[i0 + sub] : -1;
        float w_reg = 0.f;
        if (myidx >= 0) {
            float sc = ss[myidx * 4 + hd] + sd_h;
            sc = fmaxf(sc, 0.2f * sc);
            w_reg = __expf(sc);
        }
        #pragma unroll 4
        for (int j = 0; j < rem; ++j) {
            int s = __shfl(myidx, j);
            float w = __shfl(w_reg, hd16 + j);
            float2 f = __half22float2(h2[s * 64 + lane]);
            acc0 = fmaf(w, f.x, acc0);
            acc1 = fmaf(w, f.y, acc1);
            den += w;
        }
    }

    float inv = 1.f / den;
    float2 b2 = ((const float2*)bias)[lane];
    float o0 = fmaxf(fmaf(acc0, inv, b2.x), 0.f);
    float o1 = fmaxf(fmaf(acc1, inv, b2.y), 0.f);
    __half2 ov = __floats2half2_rn(o0, o1);
    *(unsigned int*)&out[v * 128 + 2 * lane] = *(unsigned int*)&ov;
}

// ---- fused alpha + gather, layer 4, BOTH branches -> single d_out write --
__global__ __launch_bounds__(256) void gather64_both(
        const __half* __restrict__ h0, const __half* __restrict__ h1,
        const float* __restrict__ ss0, const float* __restrict__ ss1,
        const float* __restrict__ sd0, const float* __restrict__ sd1,
        const int* __restrict__ rp0, const int* __restrict__ rp1,
        const unsigned short* __restrict__ csr0,
        const unsigned short* __restrict__ csr1,
        const float* __restrict__ bias0, const float* __restrict__ bias1,
        float* __restrict__ out, int n) {
    int wid = threadIdx.x >> 6, lane = threadIdx.x & 63;
    int v = blockIdx.x * 4 + wid;
    if (v >= n) return;
    int sub = lane & 15;
    float og = 0.f;

    #pragma unroll
    for (int br = 0; br < 2; ++br) {
        const __half* h   = br ? h1 : h0;
        const float* ss   = br ? ss1 : ss0;
        const float* sd   = br ? sd1 : sd0;
        const int* rowptr = br ? rp1 : rp0;
        const unsigned short* csr = br ? csr1 : csr0;
        const float* bias = br ? bias1 : bias0;
        int beg = rowptr[v], end = rowptr[v + 1];
        float sd_v = sd[v];
        float acc = 0.f, den = 0.f;
        int i0 = beg;
        for (; i0 + 16 <= end; i0 += 16) {
            int myidx = csr[i0 + sub];
            unsigned short hv[16];
            #pragma unroll
            for (int j = 0; j < 16; ++j) {
                int s = __shfl(myidx, j);
                hv[j] = *(const unsigned short*)&h[s * 64 + lane];
            }
            float sc = ss[myidx] + sd_v;
            sc = fmaxf(sc, 0.2f * sc);
            float w_reg = __expf(sc);
            #pragma unroll
            for (int j = 0; j < 16; ++j) {
                float w = __shfl(w_reg, j);
                float f = __half2float(*(const __half*)&hv[j]);
                acc = fmaf(w, f, acc);
                den += w;
            }
        }
        int rem = end - i0;
        if (rem > 0) {
            int myidx = (sub < rem) ? (int)csr[i0 + sub] : -1;
            float w_reg = 0.f;
            if (myidx >= 0) {
                float sc = ss[myidx] + sd_v;
                sc = fmaxf(sc, 0.2f * sc);
                w_reg = __expf(sc);
            }
            #pragma unroll 4
            for (int j = 0; j < rem; ++j) {
                int s = __shfl(myidx, j);
                float w = __shfl(w_reg, j);
                float f = __half2float(h[s * 64 + lane]);
                acc = fmaf(w, f, acc);
                den += w;
            }
        }
        float o = acc / den + bias[lane];
        og += 0.5f / (1.f + __expf(-o));
    }
    out[(size_t)v * 64 + lane] = og;
}

extern "C" void kernel_launch(void* const* d_in, const int* in_sizes, int n_in,
                              void* d_out, int out_size, void* d_ws, size_t ws_size,
                              hipStream_t stream) {
    const int N = in_sizes[0] / 128;      // 20000
    const int E = in_sizes[1] / 2;        // 320000
    const int TOT = E + N;                // edges incl. self loops
    const int NP = N + 4;                 // rowptr stride
    const int NBUK = (N + 63) >> 6;       // 313 buckets of 64 nodes
    const int NBLK = 256;                 // count/scatter blocks per branch

    const float* x1 = (const float*)d_in[0];
    const int*   ei1 = (const int*)d_in[1];
    const float* x2 = (const float*)d_in[2];
    const int*   ei2 = (const int*)d_in[3];
    void* const* P0 = d_in + 4;
    void* const* P1 = d_in + 20;

    // workspace layout (8B-aligned chunks)
    char* w = (char*)d_ws;
    f16* bufX = (f16*)w;                 w += (size_t)2 * N * 128 * 2;
    f16* bufH = (f16*)w;                 w += (size_t)2 * N * 128 * 2;
    float* s_src = (float*)w;            w += (size_t)2 * N * 4 * 4;
    float* s_dst = (float*)w;            w += (size_t)2 * N * 4 * 4;
    int* rowptr = (int*)w;               w += (size_t)2 * NP * 4;
    unsigned short* csr_src = (unsigned short*)w;  w += (size_t)2 * TOT * 2 + 4;
    int* carr = (int*)w;                 w += (size_t)2 * NBLK * NBKP * 4;
    int* btot = (int*)w;                 w += (size_t)2 * NBKP * 4;
    int* bbase = (int*)w;                w += (size_t)2 * (NBUK + 1) * 4 + 8;
    unsigned int* pbuf = (unsigned int*)w;  w += (size_t)2 * TOT * 4;
    f16* wsd = (f16*)w;                  w += (size_t)8 * 2048 * 2;

    dim3 blk(256);
    int gWave  = (N + 3) / 4;             // wave-per-node kernels

    // ---- all score-weight tiles (weights-only dependency) ---------------
    WsdArgs wa;
    for (int l = 0; l < 4; ++l) {
        int o = (l < 3) ? l * 4 : 12;
        wa.W[l * 2 + 0]  = (const float*)P0[o + 0];
        wa.W[l * 2 + 1]  = (const float*)P1[o + 0];
        wa.as[l * 2 + 0] = (const float*)P0[o + 1];
        wa.as[l * 2 + 1] = (const float*)P1[o + 1];
        wa.ad[l * 2 + 0] = (const float*)P0[o + 2];
        wa.ad[l * 2 + 1] = (const float*)P1[o + 2];
    }
    wsd_all<<<dim3(8, 2, 4), blk, 0, stream>>>(wa, wsd);

    // ---- CSR build: bucketed counting sort, no global atomics -----------
    bucket_count<<<dim3(NBLK, 2), blk, 0, stream>>>(ei1, ei2, carr, NBUK, E, TOT);
    bucket_scan1<<<dim3(NBUK, 2), blk, 0, stream>>>(carr, btot, NBLK);
    bucket_scan2<<<dim3(1, 2), dim3(512), 0, stream>>>(btot, bbase, NBUK);
    bucket_scatter<<<dim3(NBLK, 2), blk, 0, stream>>>(ei1, ei2, carr, bbase,
                                                      pbuf, NBUK, E, TOT);
    bucket_finalize<<<dim3(NBUK, 2), blk, 0, stream>>>(pbuf, bbase, rowptr,
                                                       csr_src, N, NBUK, TOT, NP);

    // ---- layers 1..3 (128 -> 4x32, relu), gathers per-branch ------------
    for (int l = 0; l < 3; ++l) {
        if (l == 0)
            gemm_mfma<float><<<dim3(128, 2, 2), blk, 0, stream>>>(
                x1, x2,
                (const float*)P0[0], (const float*)P1[0],
                wsd + (size_t)l * 4096, bufH, s_src, s_dst, N, 128, 4);
        else
            gemm_mfma<f16><<<dim3(128, 2, 2), blk, 0, stream>>>(
                bufX, bufX + (size_t)N * 128,
                (const float*)P0[l*4+0], (const float*)P1[l*4+0],
                wsd + (size_t)l * 4096, bufH, s_src, s_dst, N, 128, 4);
        for (int b = 0; b < 2; ++b)
            gather128_f<<<gWave, blk, 0, stream>>>(
                (const __half2*)(bufH + (size_t)b * N * 128),
                s_src + (size_t)b * N * 4, s_dst + (size_t)b * N * 4,
                rowptr + (size_t)b * NP, csr_src + (size_t)b * TOT,
                (const float*)(b ? P1[l*4+3] : P0[l*4+3]),
                bufX + (size_t)b * N * 128, N);
    }

    // ---- layer 4 (128 -> 1x64, sigmoid, both branches -> d_out) ---------
    gemm_mfma<f16><<<dim3(128, 1, 2), blk, 0, stream>>>(
        bufX, bufX + (size_t)N * 128,
        (const float*)P0[12], (const float*)P1[12],
        wsd + (size_t)3 * 4096, bufH, s_src, s_dst, N, 64, 1);
    gather64_both<<<gWave, blk, 0, stream>>>(
        (const __half*)bufH, (const __half*)(bufH + (size_t)N * 128),
        s_src, s_src + (size_t)N * 4, s_dst, s_dst + (size_t)N * 4,
        rowptr, rowptr + NP, csr_src, csr_src + (size_t)TOT,
        (const float*)P0[15], (const float*)P1[15],
        (float*)d_out, N);
}

// Round 18
// 218.842 us; speedup vs baseline: 1.3125x; 1.0771x over previous
//
#include <hip/hip_runtime.h>
#include <hip/hip_fp16.h>
#include <math.h>

// ---------------------------------------------------------------------------
// dual GAT (2 branches x 4 GATConv layers), N=20000 nodes, E=320000 edges.
// R17 = R16 (best: 235.7us) with ONE change:
//  - per layer, the two per-branch gather128_f dispatches merged into ONE
//    dispatch with XCD-partitioned branches: branch = (blockIdx&7)>=4, so
//    HW round-robin places branch 0 on XCDs 0-3, branch 1 on XCDs 4-7.
//    Same per-XCD L2 working set as the split version (one branch's 5.1MB h
//    per XCD), but branches run concurrently + 3 fewer serialized dispatches.
//    (XCD mapping is a perf heuristic only — correctness is placement-free.)
// ---------------------------------------------------------------------------

#define WAVE 64
#define NBKP 320   // padded bucket count (N/64 = 313 actual)

typedef _Float16 f16;
typedef f16 f16x8 __attribute__((ext_vector_type(8)));
typedef f16 f16x4 __attribute__((ext_vector_type(4)));
typedef float f32x4 __attribute__((ext_vector_type(4)));

// ---- stage 1: per-(block,bucket) counts (LDS hist, no global atomics) ----
__global__ __launch_bounds__(256) void bucket_count(
        const int* __restrict__ ei0, const int* __restrict__ ei1,
        int* __restrict__ carr, int nbuk, int E, int tot) {
    __shared__ int h[NBKP];
    int br = blockIdx.y;
    const int* ei = br ? ei1 : ei0;
    for (int i = threadIdx.x; i < NBKP; i += 256) h[i] = 0;
    __syncthreads();
    for (int t = blockIdx.x * 256 + threadIdx.x; t < tot; t += 256 * 256) {
        int dst = (t < E) ? ei[E + t] : (t - E);
        atomicAdd(&h[dst >> 6], 1);
    }
    __syncthreads();
    int* c = carr + ((size_t)br * gridDim.x + blockIdx.x) * NBKP;
    for (int i = threadIdx.x; i < NBKP; i += 256) c[i] = h[i];
}

// ---- stage 2a: per-bucket exclusive prefix over the 256 blocks -----------
__global__ __launch_bounds__(256) void bucket_scan1(
        int* __restrict__ carr, int* __restrict__ btot, int nblk) {
    __shared__ int smem[256];
    int br = blockIdx.y, k = blockIdx.x;
    size_t idx = ((size_t)br * nblk + threadIdx.x) * NBKP + k;
    int v = carr[idx];
    smem[threadIdx.x] = v;
    __syncthreads();
    #pragma unroll
    for (int off = 1; off < 256; off <<= 1) {
        int t = (threadIdx.x >= off) ? smem[threadIdx.x - off] : 0;
        __syncthreads();
        smem[threadIdx.x] += t;
        __syncthreads();
    }
    carr[idx] = smem[threadIdx.x] - v;            // exclusive prefix
    if (threadIdx.x == 255) btot[br * NBKP + k] = smem[255];
}

// ---- stage 2b: bucket bases (512-thread LDS scan over bucket totals) -----
__global__ __launch_bounds__(512) void bucket_scan2(
        const int* __restrict__ btot, int* __restrict__ bbase, int nbuk) {
    __shared__ int smem[512];
    int br = blockIdx.y;
    int v = (threadIdx.x < nbuk) ? btot[br * NBKP + threadIdx.x] : 0;
    smem[threadIdx.x] = v;
    __syncthreads();
    #pragma unroll
    for (int off = 1; off < 512; off <<= 1) {
        int t = (threadIdx.x >= off) ? smem[threadIdx.x - off] : 0;
        __syncthreads();
        smem[threadIdx.x] += t;
        __syncthreads();
    }
    int* bb = bbase + br * (nbuk + 1);
    if (threadIdx.x < nbuk) bb[threadIdx.x] = smem[threadIdx.x] - v;
    if (threadIdx.x == nbuk - 1) bb[nbuk] = smem[threadIdx.x];
}

// ---- stage 3: deterministic-slot pair scatter (uint-packed dst|src) ------
__global__ __launch_bounds__(256) void bucket_scatter(
        const int* __restrict__ ei0, const int* __restrict__ ei1,
        const int* __restrict__ carr, const int* __restrict__ bbase,
        unsigned int* __restrict__ pbuf, int nbuk, int E, int tot) {
    __shared__ int base_s[NBKP];
    __shared__ int h[NBKP];
    int br = blockIdx.y;
    const int* ei = br ? ei1 : ei0;
    const int* offb = carr + ((size_t)br * gridDim.x + blockIdx.x) * NBKP;
    const int* bb = bbase + br * (nbuk + 1);
    unsigned int* pb = pbuf + (size_t)br * tot;
    for (int i = threadIdx.x; i < NBKP; i += 256) {
        h[i] = 0;
        base_s[i] = (i < nbuk) ? (bb[i] + offb[i]) : 0;
    }
    __syncthreads();
    for (int t = blockIdx.x * 256 + threadIdx.x; t < tot; t += 256 * 256) {
        int src, dst;
        if (t < E) { src = ei[t]; dst = ei[E + t]; }
        else       { src = dst = t - E; }
        int k = dst >> 6;
        int r = atomicAdd(&h[k], 1);        // LDS rank
        pb[base_s[k] + r] = ((unsigned)dst << 16) | (unsigned)src;
    }
}

// ---- stage 4: per-bucket exact CSR (ushort src) + rowptr -----------------
__global__ __launch_bounds__(256) void bucket_finalize(
        const unsigned int* __restrict__ pbuf, const int* __restrict__ bbase,
        int* __restrict__ rowptrb, unsigned short* __restrict__ csrb,
        int n, int nbuk, int tot, int np) {
    __shared__ int h64[64], excl[64], cur[64];
    int br = blockIdx.y, k = blockIdx.x;
    const int* bb = bbase + br * (nbuk + 1);
    const unsigned int* pb = pbuf + (size_t)br * tot;
    int base = bb[k], endb = bb[k + 1], cnt = endb - base;
    int* rp = rowptrb + (size_t)br * np;
    unsigned short* cs = csrb + (size_t)br * tot;
    int d0 = k << 6;
    int nn = min(64, n - d0);
    if (threadIdx.x < 64) h64[threadIdx.x] = 0;
    __syncthreads();
    for (int i = threadIdx.x; i < cnt; i += 256) {
        int dst = (int)(pb[base + i] >> 16);
        atomicAdd(&h64[dst & 63], 1);
    }
    __syncthreads();
    if (threadIdx.x == 0) {
        int run = 0;
        for (int j = 0; j < 64; ++j) { excl[j] = run; run += h64[j]; }
    }
    __syncthreads();
    if (threadIdx.x < 64) cur[threadIdx.x] = excl[threadIdx.x];
    if (threadIdx.x < nn) rp[d0 + threadIdx.x] = base + excl[threadIdx.x];
    if (k == nbuk - 1 && threadIdx.x == 64) rp[n] = endb;
    __syncthreads();
    for (int i = threadIdx.x; i < cnt; i += 256) {
        unsigned int p = pb[base + i];
        int dst = (int)(p >> 16);
        unsigned short src = (unsigned short)(p & 0xFFFFu);
        int slot = atomicAdd(&cur[dst & 63], 1);
        cs[base + slot] = src;
    }
}

// ---- score-weight tiles for ALL layers in one launch ---------------------
struct WsdArgs {
    const float* W[8];    // [layer*2+branch]
    const float* as[8];
    const float* ad[8];
};

__global__ __launch_bounds__(256) void wsd_all(WsdArgs a, f16* __restrict__ wsd) {
    int l = blockIdx.z, b = blockIdx.y;
    int fout = (l == 3) ? 64 : 128;
    int H    = (l == 3) ? 1 : 4;
    int C    = (l == 3) ? 64 : 32;
    const float* W   = a.W[l * 2 + b];
    const float* a_s = a.as[l * 2 + b];
    const float* a_d = a.ad[l * 2 + b];
    f16* out = wsd + ((size_t)(l * 2 + b)) * 16 * 128;
    int k = blockIdx.x * 16 + (threadIdx.x & 15);
    int sc = threadIdx.x >> 4;
    float sum = 0.f;
    if (sc < 2 * H) {
        int hd = (sc < H) ? sc : sc - H;
        const float* av = (sc < H) ? a_s : a_d;
        const float4* Wr = (const float4*)(W + (size_t)k * fout + hd * C);
        const float4* ar = (const float4*)(av + hd * C);
        for (int c = 0; c < (C >> 2); ++c) {
            float4 wv = Wr[c]; float4 a4 = ar[c];
            sum += wv.x * a4.x + wv.y * a4.y + wv.z * a4.z + wv.w * a4.w;
        }
    }
    out[sc * 128 + k] = (f16)sum;
}

// ---- MFMA GEMM: h = x@W (f32 acc, fp16 out) + score cols ----------------
template <typename XT>
__global__ __launch_bounds__(256) void gemm_mfma(
        const XT* __restrict__ x0, const XT* __restrict__ x1,
        const float* __restrict__ W0, const float* __restrict__ W1,
        const f16* __restrict__ wsd,
        f16* __restrict__ hb, float* __restrict__ ssb, float* __restrict__ sdb,
        int n, int fout, int H) {
    __shared__ f16 xl[64 * 136];
    __shared__ f16 wl[80 * 136];
    int b = blockIdx.z;
    const XT* x = b ? x1 : x0;
    const float* W = b ? W1 : W0;
    f16* h = hb + (size_t)b * n * 128;
    float* ss = ssb + (size_t)b * n * 4;
    float* sd = sdb + (size_t)b * n * 4;
    int colbase = blockIdx.y * 64;
    bool last = (blockIdx.y == gridDim.y - 1);
    int lane = threadIdx.x & 63, w = threadIdx.x >> 6;

    {
        int c = threadIdx.x & 63, kb = (threadIdx.x >> 6) * 32;
        #pragma unroll 8
        for (int j = 0; j < 32; ++j)
            wl[c * 136 + kb + j] = (f16)W[(size_t)(kb + j) * fout + colbase + c];
    }
    if (last) {
        int c = threadIdx.x & 15, kb = (threadIdx.x >> 4) * 8;
        *(f16x8*)&wl[(64 + c) * 136 + kb] =
            *(const f16x8*)&wsd[(size_t)b * 2048 + c * 128 + kb];
    }
    __syncthreads();

    f16x8 B[5][4];
    #pragma unroll
    for (int ct = 0; ct < 5; ++ct)
        #pragma unroll
        for (int kc = 0; kc < 4; ++kc)
            B[ct][kc] = *(const f16x8*)
                &wl[(ct * 16 + (lane & 15)) * 136 + kc * 32 + (lane >> 4) * 8];

    for (int base = blockIdx.x * 64; base < n; base += gridDim.x * 64) {
        __syncthreads();
        {
            int r = threadIdx.x >> 2, k0 = (threadIdx.x & 3) * 32;
            int row = base + r;
            if (row < n) {
                if constexpr (sizeof(XT) == 4) {
                    const float4* x4 = (const float4*)x;
                    #pragma unroll
                    for (int j = 0; j < 8; ++j) {
                        float4 v = x4[(size_t)row * 32 + (k0 >> 2) + j];
                        f16x4 hv = {(f16)v.x, (f16)v.y, (f16)v.z, (f16)v.w};
                        *(f16x4*)&xl[r * 136 + k0 + 4 * j] = hv;
                    }
                } else {
                    const f16x8* x8 = (const f16x8*)x;
                    #pragma unroll
                    for (int j = 0; j < 4; ++j)
                        *(f16x8*)&xl[r * 136 + k0 + 8 * j] =
                            x8[(size_t)row * 16 + (k0 >> 3) + j];
                }
            } else {
                f16x4 z = {(f16)0.f, (f16)0.f, (f16)0.f, (f16)0.f};
                #pragma unroll
                for (int j = 0; j < 8; ++j)
                    *(f16x4*)&xl[r * 136 + k0 + 4 * j] = z;
            }
        }
        __syncthreads();

        f16x8 A[4];
        #pragma unroll
        for (int kc = 0; kc < 4; ++kc)
            A[kc] = *(const f16x8*)
                &xl[(w * 16 + (lane & 15)) * 136 + kc * 32 + (lane >> 4) * 8];

        f32x4 acc[5];
        #pragma unroll
        for (int ct = 0; ct < 5; ++ct) acc[ct] = (f32x4){0.f, 0.f, 0.f, 0.f};
        #pragma unroll
        for (int ct = 0; ct < 5; ++ct)
            #pragma unroll
            for (int kc = 0; kc < 4; ++kc)
                acc[ct] = __builtin_amdgcn_mfma_f32_16x16x32_f16(
                    A[kc], B[ct][kc], acc[ct], 0, 0, 0);

        int r0 = base + w * 16 + (lane >> 4) * 4;
        int c0 = lane & 15;
        #pragma unroll
        for (int ct = 0; ct < 4; ++ct) {
            int col = colbase + ct * 16 + c0;
            #pragma unroll
            for (int j = 0; j < 4; ++j) {
                int row = r0 + j;
                if (row < n) h[(size_t)row * fout + col] = (f16)acc[ct][j];
            }
        }
        if (last) {
            #pragma unroll
            for (int j = 0; j < 4; ++j) {
                int row = r0 + j;
                if (row < n) {
                    float v = acc[4][j];
                    if (c0 < H)          ss[(size_t)row * H + c0] = v;
                    else if (c0 < 2 * H) sd[(size_t)row * H + c0 - H] = v;
                }
            }
        }
    }
}

// ---- fused alpha + gather, 128-wide layers: both branches, XCD-split -----
// branch = (blockIdx&7)>=4 so each XCD sees one branch's h only (perf hint).
// Loop body identical to R16.
__global__ __launch_bounds__(256) void gather128_f(
        const __half2* __restrict__ h2b, const float* __restrict__ ssb,
        const float* __restrict__ sdb, const int* __restrict__ rpb,
        const unsigned short* __restrict__ csrb,
        const float* __restrict__ bias0, const float* __restrict__ bias1,
        f16* __restrict__ outb, int n, int tot, int np, int nbpb) {
    int flat = blockIdx.x;
    int slot = flat & 7, g = flat >> 3;
    int br = slot >> 2;
    int nb = g * 4 + (slot & 3);
    if (nb >= nbpb) return;

    const __half2* h2 = h2b + (size_t)br * n * 64;
    const float* ss = ssb + (size_t)br * n * 4;
    const float* sd = sdb + (size_t)br * n * 4;
    const int* rowptr = rpb + (size_t)br * np;
    const unsigned short* csr = csrb + (size_t)br * tot;
    const float* bias = br ? bias1 : bias0;
    f16* out = outb + (size_t)br * n * 128;

    int wid = threadIdx.x >> 6, lane = threadIdx.x & 63;
    int v = nb * 4 + wid;
    if (v >= n) return;
    int beg = rowptr[v], end = rowptr[v + 1];
    int hd = lane >> 4;
    int sub = lane & 15;
    int hd16 = hd * 16;
    float sd_h = sd[v * 4 + hd];

    float acc0 = 0.f, acc1 = 0.f, den = 0.f;
    int i0 = beg;
    for (; i0 + 16 <= end; i0 += 16) {
        int myidx = csr[i0 + sub];
        unsigned hv[16];
        #pragma unroll
        for (int j = 0; j < 16; ++j) {
            int s = __shfl(myidx, j);
            hv[j] = *(const unsigned*)&h2[s * 64 + lane];
        }
        float sc = ss[myidx * 4 + hd] + sd_h;
        sc = fmaxf(sc, 0.2f * sc);
        float w_reg = __expf(sc);
        #pragma unroll
        for (int j = 0; j < 16; ++j) {
            float w = __shfl(w_reg, hd16 + j);
            float2 f = __half22float2(*(const __half2*)&hv[j]);
            acc0 = fmaf(w, f.x, acc0);
            acc1 = fmaf(w, f.y, acc1);
            den += w;
        }
    }
    int rem = end - i0;
    if (rem > 0) {
        int myidx = (sub < rem) ? (int)csr[i0 + sub] : -1;
        float w_reg = 0.f;
        if (myidx >= 0) {
            float sc = ss[myidx * 4 + hd] + sd_h;
            sc = fmaxf(sc, 0.2f * sc);
            w_reg = __expf(sc);
        }
        #pragma unroll 4
        for (int j = 0; j < rem; ++j) {
            int s = __shfl(myidx, j);
            float w = __shfl(w_reg, hd16 + j);
            float2 f = __half22float2(h2[s * 64 + lane]);
            acc0 = fmaf(w, f.x, acc0);
            acc1 = fmaf(w, f.y, acc1);
            den += w;
        }
    }

    float inv = 1.f / den;
    float2 b2 = ((const float2*)bias)[lane];
    float o0 = fmaxf(fmaf(acc0, inv, b2.x), 0.f);
    float o1 = fmaxf(fmaf(acc1, inv, b2.y), 0.f);
    __half2 ov = __floats2half2_rn(o0, o1);
    *(unsigned int*)&out[v * 128 + 2 * lane] = *(unsigned int*)&ov;
}

// ---- fused alpha + gather, layer 4, BOTH branches -> single d_out write --
__global__ __launch_bounds__(256) void gather64_both(
        const __half* __restrict__ h0, const __half* __restrict__ h1,
        const float* __restrict__ ss0, const float* __restrict__ ss1,
        const float* __restrict__ sd0, const float* __restrict__ sd1,
        const int* __restrict__ rp0, const int* __restrict__ rp1,
        const unsigned short* __restrict__ csr0,
        const unsigned short* __restrict__ csr1,
        const float* __restrict__ bias0, const float* __restrict__ bias1,
        float* __restrict__ out, int n) {
    int wid = threadIdx.x >> 6, lane = threadIdx.x & 63;
    int v = blockIdx.x * 4 + wid;
    if (v >= n) return;
    int sub = lane & 15;
    float og = 0.f;

    #pragma unroll
    for (int br = 0; br < 2; ++br) {
        const __half* h   = br ? h1 : h0;
        const float* ss   = br ? ss1 : ss0;
        const float* sd   = br ? sd1 : sd0;
        const int* rowptr = br ? rp1 : rp0;
        const unsigned short* csr = br ? csr1 : csr0;
        const float* bias = br ? bias1 : bias0;
        int beg = rowptr[v], end = rowptr[v + 1];
        float sd_v = sd[v];
        float acc = 0.f, den = 0.f;
        int i0 = beg;
        for (; i0 + 16 <= end; i0 += 16) {
            int myidx = csr[i0 + sub];
            unsigned short hv[16];
            #pragma unroll
            for (int j = 0; j < 16; ++j) {
                int s = __shfl(myidx, j);
                hv[j] = *(const unsigned short*)&h[s * 64 + lane];
            }
            float sc = ss[myidx] + sd_v;
            sc = fmaxf(sc, 0.2f * sc);
            float w_reg = __expf(sc);
            #pragma unroll
            for (int j = 0; j < 16; ++j) {
                float w = __shfl(w_reg, j);
                float f = __half2float(*(const __half*)&hv[j]);
                acc = fmaf(w, f, acc);
                den += w;
            }
        }
        int rem = end - i0;
        if (rem > 0) {
            int myidx = (sub < rem) ? (int)csr[i0 + sub] : -1;
            float w_reg = 0.f;
            if (myidx >= 0) {
                float sc = ss[myidx] + sd_v;
                sc = fmaxf(sc, 0.2f * sc);
                w_reg = __expf(sc);
            }
            #pragma unroll 4
            for (int j = 0; j < rem; ++j) {
                int s = __shfl(myidx, j);
                float w = __shfl(w_reg, j);
                float f = __half2float(h[s * 64 + lane]);
                acc = fmaf(w, f, acc);
                den += w;
            }
        }
        float o = acc / den + bias[lane];
        og += 0.5f / (1.f + __expf(-o));
    }
    out[(size_t)v * 64 + lane] = og;
}

extern "C" void kernel_launch(void* const* d_in, const int* in_sizes, int n_in,
                              void* d_out, int out_size, void* d_ws, size_t ws_size,
                              hipStream_t stream) {
    const int N = in_sizes[0] / 128;      // 20000
    const int E = in_sizes[1] / 2;        // 320000
    const int TOT = E + N;                // edges incl. self loops
    const int NP = N + 4;                 // rowptr stride
    const int NBUK = (N + 63) >> 6;       // 313 buckets of 64 nodes
    const int NBLK = 256;                 // count/scatter blocks per branch

    const float* x1 = (const float*)d_in[0];
    const int*   ei1 = (const int*)d_in[1];
    const float* x2 = (const float*)d_in[2];
    const int*   ei2 = (const int*)d_in[3];
    void* const* P0 = d_in + 4;
    void* const* P1 = d_in + 20;

    // workspace layout (8B-aligned chunks)
    char* w = (char*)d_ws;
    f16* bufX = (f16*)w;                 w += (size_t)2 * N * 128 * 2;
    f16* bufH = (f16*)w;                 w += (size_t)2 * N * 128 * 2;
    float* s_src = (float*)w;            w += (size_t)2 * N * 4 * 4;
    float* s_dst = (float*)w;            w += (size_t)2 * N * 4 * 4;
    int* rowptr = (int*)w;               w += (size_t)2 * NP * 4;
    unsigned short* csr_src = (unsigned short*)w;  w += (size_t)2 * TOT * 2 + 4;
    int* carr = (int*)w;                 w += (size_t)2 * NBLK * NBKP * 4;
    int* btot = (int*)w;                 w += (size_t)2 * NBKP * 4;
    int* bbase = (int*)w;                w += (size_t)2 * (NBUK + 1) * 4 + 8;
    unsigned int* pbuf = (unsigned int*)w;  w += (size_t)2 * TOT * 4;
    f16* wsd = (f16*)w;                  w += (size_t)8 * 2048 * 2;

    dim3 blk(256);
    int gWave  = (N + 3) / 4;             // blocks per branch (4 nodes/block)
    int gSplit = 8 * ((gWave + 3) / 4);   // XCD-partitioned dual-branch grid

    // ---- all score-weight tiles (weights-only dependency) ---------------
    WsdArgs wa;
    for (int l = 0; l < 4; ++l) {
        int o = (l < 3) ? l * 4 : 12;
        wa.W[l * 2 + 0]  = (const float*)P0[o + 0];
        wa.W[l * 2 + 1]  = (const float*)P1[o + 0];
        wa.as[l * 2 + 0] = (const float*)P0[o + 1];
        wa.as[l * 2 + 1] = (const float*)P1[o + 1];
        wa.ad[l * 2 + 0] = (const float*)P0[o + 2];
        wa.ad[l * 2 + 1] = (const float*)P1[o + 2];
    }
    wsd_all<<<dim3(8, 2, 4), blk, 0, stream>>>(wa, wsd);

    // ---- CSR build: bucketed counting sort, no global atomics -----------
    bucket_count<<<dim3(NBLK, 2), blk, 0, stream>>>(ei1, ei2, carr, NBUK, E, TOT);
    bucket_scan1<<<dim3(NBUK, 2), blk, 0, stream>>>(carr, btot, NBLK);
    bucket_scan2<<<dim3(1, 2), dim3(512), 0, stream>>>(btot, bbase, NBUK);
    bucket_scatter<<<dim3(NBLK, 2), blk, 0, stream>>>(ei1, ei2, carr, bbase,
                                                      pbuf, NBUK, E, TOT);
    bucket_finalize<<<dim3(NBUK, 2), blk, 0, stream>>>(pbuf, bbase, rowptr,
                                                       csr_src, N, NBUK, TOT, NP);

    // ---- layers 1..3 (128 -> 4x32, relu), both-branch XCD-split gather --
    for (int l = 0; l < 3; ++l) {
        if (l == 0)
            gemm_mfma<float><<<dim3(128, 2, 2), blk, 0, stream>>>(
                x1, x2,
                (const float*)P0[0], (const float*)P1[0],
                wsd + (size_t)l * 4096, bufH, s_src, s_dst, N, 128, 4);
        else
            gemm_mfma<f16><<<dim3(128, 2, 2), blk, 0, stream>>>(
                bufX, bufX + (size_t)N * 128,
                (const float*)P0[l*4+0], (const float*)P1[l*4+0],
                wsd + (size_t)l * 4096, bufH, s_src, s_dst, N, 128, 4);
        gather128_f<<<gSplit, blk, 0, stream>>>(
            (const __half2*)bufH, s_src, s_dst, rowptr, csr_src,
            (const float*)P0[l*4+3], (const float*)P1[l*4+3],
            bufX, N, TOT, NP, gWave);
    }

    // ---- layer 4 (128 -> 1x64, sigmoid, both branches -> d_out) ---------
    gemm_mfma<f16><<<dim3(128, 1, 2), blk, 0, stream>>>(
        bufX, bufX + (size_t)N * 128,
        (const float*)P0[12], (const float*)P1[12],
        wsd + (size_t)3 * 4096, bufH, s_src, s_dst, N, 64, 1);
    gather64_both<<<gWave, blk, 0, stream>>>(
        (const __half*)bufH, (const __half*)(bufH + (size_t)N * 128),
        s_src, s_src + (size_t)N * 4, s_dst, s_dst + (size_t)N * 4,
        rowptr, rowptr + NP, csr_src, csr_src + (size_t)TOT,
        (const float*)P0[15], (const float*)P1[15],
        (float*)d_out, N);
}

// Round 19
// 216.782 us; speedup vs baseline: 1.3249x; 1.0095x over previous
//
#include <hip/hip_runtime.h>
#include <hip/hip_fp16.h>
#include <math.h>

// ---------------------------------------------------------------------------
// dual GAT (2 branches x 4 GATConv layers), N=20000 nodes, E=320000 edges.
// R18 = R17 (best: 218.8us) with two heterogeneous dispatch merges (no loop
// body changes):
//  - wsd_count: wsd_all || bucket_count in one dispatch (both input-only)
//  - finalize_gemm: bucket_finalize || layer-1 gemm in one dispatch
//    (independent of each other; both upstream deps satisfied in-stream)
// ---------------------------------------------------------------------------

#define WAVE 64
#define NBKP 320   // padded bucket count (N/64 = 313 actual)
#define NBLK 256   // count/scatter blocks per branch

typedef _Float16 f16;
typedef f16 f16x8 __attribute__((ext_vector_type(8)));
typedef f16 f16x4 __attribute__((ext_vector_type(4)));
typedef float f32x4 __attribute__((ext_vector_type(4)));

struct WsdArgs {
    const float* W[8];    // [layer*2+branch]
    const float* as[8];
    const float* ad[8];
};

// ---- device bodies -------------------------------------------------------

__device__ __forceinline__ void wsd_body(const WsdArgs& a, f16* __restrict__ wsd,
                                         int xk, int b, int l) {
    int fout = (l == 3) ? 64 : 128;
    int H    = (l == 3) ? 1 : 4;
    int C    = (l == 3) ? 64 : 32;
    const float* W   = a.W[l * 2 + b];
    const float* a_s = a.as[l * 2 + b];
    const float* a_d = a.ad[l * 2 + b];
    f16* out = wsd + ((size_t)(l * 2 + b)) * 16 * 128;
    int k = xk * 16 + (threadIdx.x & 15);
    int sc = threadIdx.x >> 4;
    float sum = 0.f;
    if (sc < 2 * H) {
        int hd = (sc < H) ? sc : sc - H;
        const float* av = (sc < H) ? a_s : a_d;
        const float4* Wr = (const float4*)(W + (size_t)k * fout + hd * C);
        const float4* ar = (const float4*)(av + hd * C);
        for (int c = 0; c < (C >> 2); ++c) {
            float4 wv = Wr[c]; float4 a4 = ar[c];
            sum += wv.x * a4.x + wv.y * a4.y + wv.z * a4.z + wv.w * a4.w;
        }
    }
    out[sc * 128 + k] = (f16)sum;
}

__device__ __forceinline__ void count_body(
        const int* __restrict__ ei0, const int* __restrict__ ei1,
        int* __restrict__ carr, int E, int tot, int bx, int br) {
    __shared__ int hc[NBKP];
    const int* ei = br ? ei1 : ei0;
    for (int i = threadIdx.x; i < NBKP; i += 256) hc[i] = 0;
    __syncthreads();
    for (int t = bx * 256 + threadIdx.x; t < tot; t += NBLK * 256) {
        int dst = (t < E) ? ei[E + t] : (t - E);
        atomicAdd(&hc[dst >> 6], 1);
    }
    __syncthreads();
    int* c = carr + ((size_t)br * NBLK + bx) * NBKP;
    for (int i = threadIdx.x; i < NBKP; i += 256) c[i] = hc[i];
}

__device__ __forceinline__ void finalize_body(
        const unsigned int* __restrict__ pbuf, const int* __restrict__ bbase,
        int* __restrict__ rowptrb, unsigned short* __restrict__ csrb,
        int n, int nbuk, int tot, int np, int k, int br) {
    __shared__ int h64[64], excl[64], cur[64];
    const int* bb = bbase + br * (nbuk + 1);
    const unsigned int* pb = pbuf + (size_t)br * tot;
    int base = bb[k], endb = bb[k + 1], cnt = endb - base;
    int* rp = rowptrb + (size_t)br * np;
    unsigned short* cs = csrb + (size_t)br * tot;
    int d0 = k << 6;
    int nn = min(64, n - d0);
    if (threadIdx.x < 64) h64[threadIdx.x] = 0;
    __syncthreads();
    for (int i = threadIdx.x; i < cnt; i += 256) {
        int dst = (int)(pb[base + i] >> 16);
        atomicAdd(&h64[dst & 63], 1);
    }
    __syncthreads();
    if (threadIdx.x == 0) {
        int run = 0;
        for (int j = 0; j < 64; ++j) { excl[j] = run; run += h64[j]; }
    }
    __syncthreads();
    if (threadIdx.x < 64) cur[threadIdx.x] = excl[threadIdx.x];
    if (threadIdx.x < nn) rp[d0 + threadIdx.x] = base + excl[threadIdx.x];
    if (k == nbuk - 1 && threadIdx.x == 64) rp[n] = endb;
    __syncthreads();
    for (int i = threadIdx.x; i < cnt; i += 256) {
        unsigned int p = pb[base + i];
        int dst = (int)(p >> 16);
        unsigned short src = (unsigned short)(p & 0xFFFFu);
        int slot = atomicAdd(&cur[dst & 63], 1);
        cs[base + slot] = src;
    }
}

template <typename XT>
__device__ __forceinline__ void gemm_body(
        const XT* __restrict__ x0, const XT* __restrict__ x1,
        const float* __restrict__ W0, const float* __restrict__ W1,
        const f16* __restrict__ wsd,
        f16* __restrict__ hb, float* __restrict__ ssb, float* __restrict__ sdb,
        int n, int fout, int H, int gx, int gy, int b, int gridx, int ny) {
    __shared__ f16 xl[64 * 136];
    __shared__ f16 wl[80 * 136];
    const XT* x = b ? x1 : x0;
    const float* W = b ? W1 : W0;
    f16* h = hb + (size_t)b * n * 128;
    float* ss = ssb + (size_t)b * n * 4;
    float* sd = sdb + (size_t)b * n * 4;
    int colbase = gy * 64;
    bool last = (gy == ny - 1);
    int lane = threadIdx.x & 63, w = threadIdx.x >> 6;

    {
        int c = threadIdx.x & 63, kb = (threadIdx.x >> 6) * 32;
        #pragma unroll 8
        for (int j = 0; j < 32; ++j)
            wl[c * 136 + kb + j] = (f16)W[(size_t)(kb + j) * fout + colbase + c];
    }
    if (last) {
        int c = threadIdx.x & 15, kb = (threadIdx.x >> 4) * 8;
        *(f16x8*)&wl[(64 + c) * 136 + kb] =
            *(const f16x8*)&wsd[(size_t)b * 2048 + c * 128 + kb];
    }
    __syncthreads();

    f16x8 B[5][4];
    #pragma unroll
    for (int ct = 0; ct < 5; ++ct)
        #pragma unroll
        for (int kc = 0; kc < 4; ++kc)
            B[ct][kc] = *(const f16x8*)
                &wl[(ct * 16 + (lane & 15)) * 136 + kc * 32 + (lane >> 4) * 8];

    for (int base = gx * 64; base < n; base += gridx * 64) {
        __syncthreads();
        {
            int r = threadIdx.x >> 2, k0 = (threadIdx.x & 3) * 32;
            int row = base + r;
            if (row < n) {
                if constexpr (sizeof(XT) == 4) {
                    const float4* x4 = (const float4*)x;
                    #pragma unroll
                    for (int j = 0; j < 8; ++j) {
                        float4 v = x4[(size_t)row * 32 + (k0 >> 2) + j];
                        f16x4 hv = {(f16)v.x, (f16)v.y, (f16)v.z, (f16)v.w};
                        *(f16x4*)&xl[r * 136 + k0 + 4 * j] = hv;
                    }
                } else {
                    const f16x8* x8 = (const f16x8*)x;
                    #pragma unroll
                    for (int j = 0; j < 4; ++j)
                        *(f16x8*)&xl[r * 136 + k0 + 8 * j] =
                            x8[(size_t)row * 16 + (k0 >> 3) + j];
                }
            } else {
                f16x4 z = {(f16)0.f, (f16)0.f, (f16)0.f, (f16)0.f};
                #pragma unroll
                for (int j = 0; j < 8; ++j)
                    *(f16x4*)&xl[r * 136 + k0 + 4 * j] = z;
            }
        }
        __syncthreads();

        f16x8 A[4];
        #pragma unroll
        for (int kc = 0; kc < 4; ++kc)
            A[kc] = *(const f16x8*)
                &xl[(w * 16 + (lane & 15)) * 136 + kc * 32 + (lane >> 4) * 8];

        f32x4 acc[5];
        #pragma unroll
        for (int ct = 0; ct < 5; ++ct) acc[ct] = (f32x4){0.f, 0.f, 0.f, 0.f};
        #pragma unroll
        for (int ct = 0; ct < 5; ++ct)
            #pragma unroll
            for (int kc = 0; kc < 4; ++kc)
                acc[ct] = __builtin_amdgcn_mfma_f32_16x16x32_f16(
                    A[kc], B[ct][kc], acc[ct], 0, 0, 0);

        int r0 = base + w * 16 + (lane >> 4) * 4;
        int c0 = lane & 15;
        #pragma unroll
        for (int ct = 0; ct < 4; ++ct) {
            int col = colbase + ct * 16 + c0;
            #pragma unroll
            for (int j = 0; j < 4; ++j) {
                int row = r0 + j;
                if (row < n) h[(size_t)row * fout + col] = (f16)acc[ct][j];
            }
        }
        if (last) {
            #pragma unroll
            for (int j = 0; j < 4; ++j) {
                int row = r0 + j;
                if (row < n) {
                    float v = acc[4][j];
                    if (c0 < H)          ss[(size_t)row * H + c0] = v;
                    else if (c0 < 2 * H) sd[(size_t)row * H + c0 - H] = v;
                }
            }
        }
    }
}

// ---- merged dispatch A: wsd_all || bucket_count --------------------------
__global__ __launch_bounds__(256) void wsd_count(
        WsdArgs a, f16* __restrict__ wsd,
        const int* __restrict__ ei0, const int* __restrict__ ei1,
        int* __restrict__ carr, int E, int tot) {
    if (blockIdx.x < 8) {
        wsd_body(a, wsd, blockIdx.x, blockIdx.y, blockIdx.z);
    } else if (blockIdx.z == 0) {
        count_body(ei0, ei1, carr, E, tot, blockIdx.x - 8, blockIdx.y);
    }
}

// ---- stage 2a: per-bucket exclusive prefix over the 256 blocks -----------
__global__ __launch_bounds__(256) void bucket_scan1(
        int* __restrict__ carr, int* __restrict__ btot, int nblk) {
    __shared__ int smem[256];
    int br = blockIdx.y, k = blockIdx.x;
    size_t idx = ((size_t)br * nblk + threadIdx.x) * NBKP + k;
    int v = carr[idx];
    smem[threadIdx.x] = v;
    __syncthreads();
    #pragma unroll
    for (int off = 1; off < 256; off <<= 1) {
        int t = (threadIdx.x >= off) ? smem[threadIdx.x - off] : 0;
        __syncthreads();
        smem[threadIdx.x] += t;
        __syncthreads();
    }
    carr[idx] = smem[threadIdx.x] - v;            // exclusive prefix
    if (threadIdx.x == 255) btot[br * NBKP + k] = smem[255];
}

// ---- stage 2b: bucket bases (512-thread LDS scan over bucket totals) -----
__global__ __launch_bounds__(512) void bucket_scan2(
        const int* __restrict__ btot, int* __restrict__ bbase, int nbuk) {
    __shared__ int smem[512];
    int br = blockIdx.y;
    int v = (threadIdx.x < nbuk) ? btot[br * NBKP + threadIdx.x] : 0;
    smem[threadIdx.x] = v;
    __syncthreads();
    #pragma unroll
    for (int off = 1; off < 512; off <<= 1) {
        int t = (threadIdx.x >= off) ? smem[threadIdx.x - off] : 0;
        __syncthreads();
        smem[threadIdx.x] += t;
        __syncthreads();
    }
    int* bb = bbase + br * (nbuk + 1);
    if (threadIdx.x < nbuk) bb[threadIdx.x] = smem[threadIdx.x] - v;
    if (threadIdx.x == nbuk - 1) bb[nbuk] = smem[threadIdx.x];
}

// ---- stage 3: deterministic-slot pair scatter (uint-packed dst|src) ------
__global__ __launch_bounds__(256) void bucket_scatter(
        const int* __restrict__ ei0, const int* __restrict__ ei1,
        const int* __restrict__ carr, const int* __restrict__ bbase,
        unsigned int* __restrict__ pbuf, int nbuk, int E, int tot) {
    __shared__ int base_s[NBKP];
    __shared__ int h[NBKP];
    int br = blockIdx.y;
    const int* ei = br ? ei1 : ei0;
    const int* offb = carr + ((size_t)br * gridDim.x + blockIdx.x) * NBKP;
    const int* bb = bbase + br * (nbuk + 1);
    unsigned int* pb = pbuf + (size_t)br * tot;
    for (int i = threadIdx.x; i < NBKP; i += 256) {
        h[i] = 0;
        base_s[i] = (i < nbuk) ? (bb[i] + offb[i]) : 0;
    }
    __syncthreads();
    for (int t = blockIdx.x * 256 + threadIdx.x; t < tot; t += 256 * 256) {
        int src, dst;
        if (t < E) { src = ei[t]; dst = ei[E + t]; }
        else       { src = dst = t - E; }
        int k = dst >> 6;
        int r = atomicAdd(&h[k], 1);        // LDS rank
        pb[base_s[k] + r] = ((unsigned)dst << 16) | (unsigned)src;
    }
}

// ---- merged dispatch B: bucket_finalize || layer-1 gemm ------------------
__global__ __launch_bounds__(256) void finalize_gemm(
        const unsigned int* __restrict__ pbuf, const int* __restrict__ bbase,
        int* __restrict__ rowptrb, unsigned short* __restrict__ csrb,
        int n, int nbuk, int tot, int np,
        const float* __restrict__ x0, const float* __restrict__ x1,
        const float* __restrict__ W0, const float* __restrict__ W1,
        const f16* __restrict__ wsd,
        f16* __restrict__ hb, float* __restrict__ ssb, float* __restrict__ sdb) {
    if ((int)blockIdx.x < nbuk) {
        if (blockIdx.z == 0)
            finalize_body(pbuf, bbase, rowptrb, csrb, n, nbuk, tot, np,
                          blockIdx.x, blockIdx.y);
    } else {
        gemm_body<float>(x0, x1, W0, W1, wsd, hb, ssb, sdb, n, 128, 4,
                         blockIdx.x - nbuk, blockIdx.y, blockIdx.z, 128, 2);
    }
}

// ---- standalone gemm (layers 2..4) ---------------------------------------
template <typename XT>
__global__ __launch_bounds__(256) void gemm_mfma(
        const XT* __restrict__ x0, const XT* __restrict__ x1,
        const float* __restrict__ W0, const float* __restrict__ W1,
        const f16* __restrict__ wsd,
        f16* __restrict__ hb, float* __restrict__ ssb, float* __restrict__ sdb,
        int n, int fout, int H) {
    gemm_body<XT>(x0, x1, W0, W1, wsd, hb, ssb, sdb, n, fout, H,
                  blockIdx.x, blockIdx.y, blockIdx.z, gridDim.x, gridDim.y);
}

// ---- fused alpha + gather, 128-wide layers: both branches, XCD-split -----
__global__ __launch_bounds__(256) void gather128_f(
        const __half2* __restrict__ h2b, const float* __restrict__ ssb,
        const float* __restrict__ sdb, const int* __restrict__ rpb,
        const unsigned short* __restrict__ csrb,
        const float* __restrict__ bias0, const float* __restrict__ bias1,
        f16* __restrict__ outb, int n, int tot, int np, int nbpb) {
    int flat = blockIdx.x;
    int slot = flat & 7, g = flat >> 3;
    int br = slot >> 2;
    int nb = g * 4 + (slot & 3);
    if (nb >= nbpb) return;

    const __half2* h2 = h2b + (size_t)br * n * 64;
    const float* ss = ssb + (size_t)br * n * 4;
    const float* sd = sdb + (size_t)br * n * 4;
    const int* rowptr = rpb + (size_t)br * np;
    const unsigned short* csr = csrb + (size_t)br * tot;
    const float* bias = br ? bias1 : bias0;
    f16* out = outb + (size_t)br * n * 128;

    int wid = threadIdx.x >> 6, lane = threadIdx.x & 63;
    int v = nb * 4 + wid;
    if (v >= n) return;
    int beg = rowptr[v], end = rowptr[v + 1];
    int hd = lane >> 4;
    int sub = lane & 15;
    int hd16 = hd * 16;
    float sd_h = sd[v * 4 + hd];

    float acc0 = 0.f, acc1 = 0.f, den = 0.f;
    int i0 = beg;
    for (; i0 + 16 <= end; i0 += 16) {
        int myidx = csr[i0 + sub];
        unsigned hv[16];
        #pragma unroll
        for (int j = 0; j < 16; ++j) {
            int s = __shfl(myidx, j);
            hv[j] = *(const unsigned*)&h2[s * 64 + lane];
        }
        float sc = ss[myidx * 4 + hd] + sd_h;
        sc = fmaxf(sc, 0.2f * sc);
        float w_reg = __expf(sc);
        #pragma unroll
        for (int j = 0; j < 16; ++j) {
            float w = __shfl(w_reg, hd16 + j);
            float2 f = __half22float2(*(const __half2*)&hv[j]);
            acc0 = fmaf(w, f.x, acc0);
            acc1 = fmaf(w, f.y, acc1);
            den += w;
        }
    }
    int rem = end - i0;
    if (rem > 0) {
        int myidx = (sub < rem) ? (int)csr[i0 + sub] : -1;
        float w_reg = 0.f;
        if (myidx >= 0) {
            float sc = ss[myidx * 4 + hd] + sd_h;
            sc = fmaxf(sc, 0.2f * sc);
            w_reg = __expf(sc);
        }
        #pragma unroll 4
        for (int j = 0; j < rem; ++j) {
            int s = __shfl(myidx, j);
            float w = __shfl(w_reg, hd16 + j);
            float2 f = __half22float2(h2[s * 64 + lane]);
            acc0 = fmaf(w, f.x, acc0);
            acc1 = fmaf(w, f.y, acc1);
            den += w;
        }
    }

    float inv = 1.f / den;
    float2 b2 = ((const float2*)bias)[lane];
    float o0 = fmaxf(fmaf(acc0, inv, b2.x), 0.f);
    float o1 = fmaxf(fmaf(acc1, inv, b2.y), 0.f);
    __half2 ov = __floats2half2_rn(o0, o1);
    *(unsigned int*)&out[v * 128 + 2 * lane] = *(unsigned int*)&ov;
}

// ---- fused alpha + gather, layer 4, BOTH branches -> single d_out write --
__global__ __launch_bounds__(256) void gather64_both(
        const __half* __restrict__ h0, const __half* __restrict__ h1,
        const float* __restrict__ ss0, const float* __restrict__ ss1,
        const float* __restrict__ sd0, const float* __restrict__ sd1,
        const int* __restrict__ rp0, const int* __restrict__ rp1,
        const unsigned short* __restrict__ csr0,
        const unsigned short* __restrict__ csr1,
        const float* __restrict__ bias0, const float* __restrict__ bias1,
        float* __restrict__ out, int n) {
    int wid = threadIdx.x >> 6, lane = threadIdx.x & 63;
    int v = blockIdx.x * 4 + wid;
    if (v >= n) return;
    int sub = lane & 15;
    float og = 0.f;

    #pragma unroll
    for (int br = 0; br < 2; ++br) {
        const __half* h   = br ? h1 : h0;
        const float* ss   = br ? ss1 : ss0;
        const float* sd   = br ? sd1 : sd0;
        const int* rowptr = br ? rp1 : rp0;
        const unsigned short* csr = br ? csr1 : csr0;
        const float* bias = br ? bias1 : bias0;
        int beg = rowptr[v], end = rowptr[v + 1];
        float sd_v = sd[v];
        float acc = 0.f, den = 0.f;
        int i0 = beg;
        for (; i0 + 16 <= end; i0 += 16) {
            int myidx = csr[i0 + sub];
            unsigned short hv[16];
            #pragma unroll
            for (int j = 0; j < 16; ++j) {
                int s = __shfl(myidx, j);
                hv[j] = *(const unsigned short*)&h[s * 64 + lane];
            }
            float sc = ss[myidx] + sd_v;
            sc = fmaxf(sc, 0.2f * sc);
            float w_reg = __expf(sc);
            #pragma unroll
            for (int j = 0; j < 16; ++j) {
                float w = __shfl(w_reg, j);
                float f = __half2float(*(const __half*)&hv[j]);
                acc = fmaf(w, f, acc);
                den += w;
            }
        }
        int rem = end - i0;
        if (rem > 0) {
            int myidx = (sub < rem) ? (int)csr[i0 + sub] : -1;
            float w_reg = 0.f;
            if (myidx >= 0) {
                float sc = ss[myidx] + sd_v;
                sc = fmaxf(sc, 0.2f * sc);
                w_reg = __expf(sc);
            }
            #pragma unroll 4
            for (int j = 0; j < rem; ++j) {
                int s = __shfl(myidx, j);
                float w = __shfl(w_reg, j);
                float f = __half2float(h[s * 64 + lane]);
                acc = fmaf(w, f, acc);
                den += w;
            }
        }
        float o = acc / den + bias[lane];
        og += 0.5f / (1.f + __expf(-o));
    }
    out[(size_t)v * 64 + lane] = og;
}

extern "C" void kernel_launch(void* const* d_in, const int* in_sizes, int n_in,
                              void* d_out, int out_size, void* d_ws, size_t ws_size,
                              hipStream_t stream) {
    const int N = in_sizes[0] / 128;      // 20000
    const int E = in_sizes[1] / 2;        // 320000
    const int TOT = E + N;                // edges incl. self loops
    const int NP = N + 4;                 // rowptr stride
    const int NBUK = (N + 63) >> 6;       // 313 buckets of 64 nodes

    const float* x1 = (const float*)d_in[0];
    const int*   ei1 = (const int*)d_in[1];
    const float* x2 = (const float*)d_in[2];
    const int*   ei2 = (const int*)d_in[3];
    void* const* P0 = d_in + 4;
    void* const* P1 = d_in + 20;

    // workspace layout (8B-aligned chunks)
    char* w = (char*)d_ws;
    f16* bufX = (f16*)w;                 w += (size_t)2 * N * 128 * 2;
    f16* bufH = (f16*)w;                 w += (size_t)2 * N * 128 * 2;
    float* s_src = (float*)w;            w += (size_t)2 * N * 4 * 4;
    float* s_dst = (float*)w;            w += (size_t)2 * N * 4 * 4;
    int* rowptr = (int*)w;               w += (size_t)2 * NP * 4;
    unsigned short* csr_src = (unsigned short*)w;  w += (size_t)2 * TOT * 2 + 4;
    int* carr = (int*)w;                 w += (size_t)2 * NBLK * NBKP * 4;
    int* btot = (int*)w;                 w += (size_t)2 * NBKP * 4;
    int* bbase = (int*)w;                w += (size_t)2 * (NBUK + 1) * 4 + 8;
    unsigned int* pbuf = (unsigned int*)w;  w += (size_t)2 * TOT * 4;
    f16* wsd = (f16*)w;                  w += (size_t)8 * 2048 * 2;

    dim3 blk(256);
    int gWave  = (N + 3) / 4;             // blocks per branch (4 nodes/block)
    int gSplit = 8 * ((gWave + 3) / 4);   // XCD-partitioned dual-branch grid

    // ---- args for merged wsd+count ---------------------------------------
    WsdArgs wa;
    for (int l = 0; l < 4; ++l) {
        int o = (l < 3) ? l * 4 : 12;
        wa.W[l * 2 + 0]  = (const float*)P0[o + 0];
        wa.W[l * 2 + 1]  = (const float*)P1[o + 0];
        wa.as[l * 2 + 0] = (const float*)P0[o + 1];
        wa.as[l * 2 + 1] = (const float*)P1[o + 1];
        wa.ad[l * 2 + 0] = (const float*)P0[o + 2];
        wa.ad[l * 2 + 1] = (const float*)P1[o + 2];
    }

    // ---- CSR build + weight tiles (merged where independent) -------------
    wsd_count<<<dim3(8 + NBLK, 2, 4), blk, 0, stream>>>(
        wa, wsd, ei1, ei2, carr, E, TOT);
    bucket_scan1<<<dim3(NBUK, 2), blk, 0, stream>>>(carr, btot, NBLK);
    bucket_scan2<<<dim3(1, 2), dim3(512), 0, stream>>>(btot, bbase, NBUK);
    bucket_scatter<<<dim3(NBLK, 2), blk, 0, stream>>>(ei1, ei2, carr, bbase,
                                                      pbuf, NBUK, E, TOT);
    // finalize || layer-1 gemm
    finalize_gemm<<<dim3(NBUK + 128, 2, 2), blk, 0, stream>>>(
        pbuf, bbase, rowptr, csr_src, N, NBUK, TOT, NP,
        x1, x2, (const float*)P0[0], (const float*)P1[0],
        wsd + (size_t)0 * 4096, bufH, s_src, s_dst);

    // ---- layer-1 gather, then layers 2..3 --------------------------------
    gather128_f<<<gSplit, blk, 0, stream>>>(
        (const __half2*)bufH, s_src, s_dst, rowptr, csr_src,
        (const float*)P0[3], (const float*)P1[3],
        bufX, N, TOT, NP, gWave);

    for (int l = 1; l < 3; ++l) {
        gemm_mfma<f16><<<dim3(128, 2, 2), blk, 0, stream>>>(
            bufX, bufX + (size_t)N * 128,
            (const float*)P0[l*4+0], (const float*)P1[l*4+0],
            wsd + (size_t)l * 4096, bufH, s_src, s_dst, N, 128, 4);
        gather128_f<<<gSplit, blk, 0, stream>>>(
            (const __half2*)bufH, s_src, s_dst, rowptr, csr_src,
            (const float*)P0[l*4+3], (const float*)P1[l*4+3],
            bufX, N, TOT, NP, gWave);
    }

    // ---- layer 4 (128 -> 1x64, sigmoid, both branches -> d_out) ---------
    gemm_mfma<f16><<<dim3(128, 1, 2), blk, 0, stream>>>(
        bufX, bufX + (size_t)N * 128,
        (const float*)P0[12], (const float*)P1[12],
        wsd + (size_t)3 * 4096, bufH, s_src, s_dst, N, 64, 1);
    gather64_both<<<gWave, blk, 0, stream>>>(
        (const __half*)bufH, (const __half*)(bufH + (size_t)N * 128),
        s_src, s_src + (size_t)N * 4, s_dst, s_dst + (size_t)N * 4,
        rowptr, rowptr + NP, csr_src, csr_src + (size_t)TOT,
        (const float*)P0[15], (const float*)P1[15],
        (float*)d_out, N);
}

// Round 20
// 191.600 us; speedup vs baseline: 1.4991x; 1.1314x over previous
//
#include <hip/hip_runtime.h>
#include <hip/hip_fp16.h>
#include <math.h>

// ---------------------------------------------------------------------------
// dual GAT (2 branches x 4 GATConv layers), N=20000 nodes, E=320000 edges.
// R19 = R18 (best: 216.8us) with ONE change in the gathers:
//  - masked uniform chunks: every iteration is a full 16-slot burst; slots
//    past the row end get w=0 and a safe dummy index (csr[beg]). Removes the
//    separate low-MLP tail path (second exposed latency round per node).
//    Arithmetic identical: masked slots add exactly 0 to acc and den.
// ---------------------------------------------------------------------------

#define WAVE 64
#define NBKP 320   // padded bucket count (N/64 = 313 actual)
#define NBLK 256   // count/scatter blocks per branch

typedef _Float16 f16;
typedef f16 f16x8 __attribute__((ext_vector_type(8)));
typedef f16 f16x4 __attribute__((ext_vector_type(4)));
typedef float f32x4 __attribute__((ext_vector_type(4)));

struct WsdArgs {
    const float* W[8];    // [layer*2+branch]
    const float* as[8];
    const float* ad[8];
};

// ---- device bodies -------------------------------------------------------

__device__ __forceinline__ void wsd_body(const WsdArgs& a, f16* __restrict__ wsd,
                                         int xk, int b, int l) {
    int fout = (l == 3) ? 64 : 128;
    int H    = (l == 3) ? 1 : 4;
    int C    = (l == 3) ? 64 : 32;
    const float* W   = a.W[l * 2 + b];
    const float* a_s = a.as[l * 2 + b];
    const float* a_d = a.ad[l * 2 + b];
    f16* out = wsd + ((size_t)(l * 2 + b)) * 16 * 128;
    int k = xk * 16 + (threadIdx.x & 15);
    int sc = threadIdx.x >> 4;
    float sum = 0.f;
    if (sc < 2 * H) {
        int hd = (sc < H) ? sc : sc - H;
        const float* av = (sc < H) ? a_s : a_d;
        const float4* Wr = (const float4*)(W + (size_t)k * fout + hd * C);
        const float4* ar = (const float4*)(av + hd * C);
        for (int c = 0; c < (C >> 2); ++c) {
            float4 wv = Wr[c]; float4 a4 = ar[c];
            sum += wv.x * a4.x + wv.y * a4.y + wv.z * a4.z + wv.w * a4.w;
        }
    }
    out[sc * 128 + k] = (f16)sum;
}

__device__ __forceinline__ void count_body(
        const int* __restrict__ ei0, const int* __restrict__ ei1,
        int* __restrict__ carr, int E, int tot, int bx, int br) {
    __shared__ int hc[NBKP];
    const int* ei = br ? ei1 : ei0;
    for (int i = threadIdx.x; i < NBKP; i += 256) hc[i] = 0;
    __syncthreads();
    for (int t = bx * 256 + threadIdx.x; t < tot; t += NBLK * 256) {
        int dst = (t < E) ? ei[E + t] : (t - E);
        atomicAdd(&hc[dst >> 6], 1);
    }
    __syncthreads();
    int* c = carr + ((size_t)br * NBLK + bx) * NBKP;
    for (int i = threadIdx.x; i < NBKP; i += 256) c[i] = hc[i];
}

__device__ __forceinline__ void finalize_body(
        const unsigned int* __restrict__ pbuf, const int* __restrict__ bbase,
        int* __restrict__ rowptrb, unsigned short* __restrict__ csrb,
        int n, int nbuk, int tot, int np, int k, int br) {
    __shared__ int h64[64], excl[64], cur[64];
    const int* bb = bbase + br * (nbuk + 1);
    const unsigned int* pb = pbuf + (size_t)br * tot;
    int base = bb[k], endb = bb[k + 1], cnt = endb - base;
    int* rp = rowptrb + (size_t)br * np;
    unsigned short* cs = csrb + (size_t)br * tot;
    int d0 = k << 6;
    int nn = min(64, n - d0);
    if (threadIdx.x < 64) h64[threadIdx.x] = 0;
    __syncthreads();
    for (int i = threadIdx.x; i < cnt; i += 256) {
        int dst = (int)(pb[base + i] >> 16);
        atomicAdd(&h64[dst & 63], 1);
    }
    __syncthreads();
    if (threadIdx.x == 0) {
        int run = 0;
        for (int j = 0; j < 64; ++j) { excl[j] = run; run += h64[j]; }
    }
    __syncthreads();
    if (threadIdx.x < 64) cur[threadIdx.x] = excl[threadIdx.x];
    if (threadIdx.x < nn) rp[d0 + threadIdx.x] = base + excl[threadIdx.x];
    if (k == nbuk - 1 && threadIdx.x == 64) rp[n] = endb;
    __syncthreads();
    for (int i = threadIdx.x; i < cnt; i += 256) {
        unsigned int p = pb[base + i];
        int dst = (int)(p >> 16);
        unsigned short src = (unsigned short)(p & 0xFFFFu);
        int slot = atomicAdd(&cur[dst & 63], 1);
        cs[base + slot] = src;
    }
}

template <typename XT>
__device__ __forceinline__ void gemm_body(
        const XT* __restrict__ x0, const XT* __restrict__ x1,
        const float* __restrict__ W0, const float* __restrict__ W1,
        const f16* __restrict__ wsd,
        f16* __restrict__ hb, float* __restrict__ ssb, float* __restrict__ sdb,
        int n, int fout, int H, int gx, int gy, int b, int gridx, int ny) {
    __shared__ f16 xl[64 * 136];
    __shared__ f16 wl[80 * 136];
    const XT* x = b ? x1 : x0;
    const float* W = b ? W1 : W0;
    f16* h = hb + (size_t)b * n * 128;
    float* ss = ssb + (size_t)b * n * 4;
    float* sd = sdb + (size_t)b * n * 4;
    int colbase = gy * 64;
    bool last = (gy == ny - 1);
    int lane = threadIdx.x & 63, w = threadIdx.x >> 6;

    {
        int c = threadIdx.x & 63, kb = (threadIdx.x >> 6) * 32;
        #pragma unroll 8
        for (int j = 0; j < 32; ++j)
            wl[c * 136 + kb + j] = (f16)W[(size_t)(kb + j) * fout + colbase + c];
    }
    if (last) {
        int c = threadIdx.x & 15, kb = (threadIdx.x >> 4) * 8;
        *(f16x8*)&wl[(64 + c) * 136 + kb] =
            *(const f16x8*)&wsd[(size_t)b * 2048 + c * 128 + kb];
    }
    __syncthreads();

    f16x8 B[5][4];
    #pragma unroll
    for (int ct = 0; ct < 5; ++ct)
        #pragma unroll
        for (int kc = 0; kc < 4; ++kc)
            B[ct][kc] = *(const f16x8*)
                &wl[(ct * 16 + (lane & 15)) * 136 + kc * 32 + (lane >> 4) * 8];

    for (int base = gx * 64; base < n; base += gridx * 64) {
        __syncthreads();
        {
            int r = threadIdx.x >> 2, k0 = (threadIdx.x & 3) * 32;
            int row = base + r;
            if (row < n) {
                if constexpr (sizeof(XT) == 4) {
                    const float4* x4 = (const float4*)x;
                    #pragma unroll
                    for (int j = 0; j < 8; ++j) {
                        float4 v = x4[(size_t)row * 32 + (k0 >> 2) + j];
                        f16x4 hv = {(f16)v.x, (f16)v.y, (f16)v.z, (f16)v.w};
                        *(f16x4*)&xl[r * 136 + k0 + 4 * j] = hv;
                    }
                } else {
                    const f16x8* x8 = (const f16x8*)x;
                    #pragma unroll
                    for (int j = 0; j < 4; ++j)
                        *(f16x8*)&xl[r * 136 + k0 + 8 * j] =
                            x8[(size_t)row * 16 + (k0 >> 3) + j];
                }
            } else {
                f16x4 z = {(f16)0.f, (f16)0.f, (f16)0.f, (f16)0.f};
                #pragma unroll
                for (int j = 0; j < 8; ++j)
                    *(f16x4*)&xl[r * 136 + k0 + 4 * j] = z;
            }
        }
        __syncthreads();

        f16x8 A[4];
        #pragma unroll
        for (int kc = 0; kc < 4; ++kc)
            A[kc] = *(const f16x8*)
                &xl[(w * 16 + (lane & 15)) * 136 + kc * 32 + (lane >> 4) * 8];

        f32x4 acc[5];
        #pragma unroll
        for (int ct = 0; ct < 5; ++ct) acc[ct] = (f32x4){0.f, 0.f, 0.f, 0.f};
        #pragma unroll
        for (int ct = 0; ct < 5; ++ct)
            #pragma unroll
            for (int kc = 0; kc < 4; ++kc)
                acc[ct] = __builtin_amdgcn_mfma_f32_16x16x32_f16(
                    A[kc], B[ct][kc], acc[ct], 0, 0, 0);

        int r0 = base + w * 16 + (lane >> 4) * 4;
        int c0 = lane & 15;
        #pragma unroll
        for (int ct = 0; ct < 4; ++ct) {
            int col = colbase + ct * 16 + c0;
            #pragma unroll
            for (int j = 0; j < 4; ++j) {
                int row = r0 + j;
                if (row < n) h[(size_t)row * fout + col] = (f16)acc[ct][j];
            }
        }
        if (last) {
            #pragma unroll
            for (int j = 0; j < 4; ++j) {
                int row = r0 + j;
                if (row < n) {
                    float v = acc[4][j];
                    if (c0 < H)          ss[(size_t)row * H + c0] = v;
                    else if (c0 < 2 * H) sd[(size_t)row * H + c0 - H] = v;
                }
            }
        }
    }
}

// ---- merged dispatch A: wsd_all || bucket_count --------------------------
__global__ __launch_bounds__(256) void wsd_count(
        WsdArgs a, f16* __restrict__ wsd,
        const int* __restrict__ ei0, const int* __restrict__ ei1,
        int* __restrict__ carr, int E, int tot) {
    if (blockIdx.x < 8) {
        wsd_body(a, wsd, blockIdx.x, blockIdx.y, blockIdx.z);
    } else if (blockIdx.z == 0) {
        count_body(ei0, ei1, carr, E, tot, blockIdx.x - 8, blockIdx.y);
    }
}

// ---- stage 2a: per-bucket exclusive prefix over the 256 blocks -----------
__global__ __launch_bounds__(256) void bucket_scan1(
        int* __restrict__ carr, int* __restrict__ btot, int nblk) {
    __shared__ int smem[256];
    int br = blockIdx.y, k = blockIdx.x;
    size_t idx = ((size_t)br * nblk + threadIdx.x) * NBKP + k;
    int v = carr[idx];
    smem[threadIdx.x] = v;
    __syncthreads();
    #pragma unroll
    for (int off = 1; off < 256; off <<= 1) {
        int t = (threadIdx.x >= off) ? smem[threadIdx.x - off] : 0;
        __syncthreads();
        smem[threadIdx.x] += t;
        __syncthreads();
    }
    carr[idx] = smem[threadIdx.x] - v;            // exclusive prefix
    if (threadIdx.x == 255) btot[br * NBKP + k] = smem[255];
}

// ---- stage 2b: bucket bases (512-thread LDS scan over bucket totals) -----
__global__ __launch_bounds__(512) void bucket_scan2(
        const int* __restrict__ btot, int* __restrict__ bbase, int nbuk) {
    __shared__ int smem[512];
    int br = blockIdx.y;
    int v = (threadIdx.x < nbuk) ? btot[br * NBKP + threadIdx.x] : 0;
    smem[threadIdx.x] = v;
    __syncthreads();
    #pragma unroll
    for (int off = 1; off < 512; off <<= 1) {
        int t = (threadIdx.x >= off) ? smem[threadIdx.x - off] : 0;
        __syncthreads();
        smem[threadIdx.x] += t;
        __syncthreads();
    }
    int* bb = bbase + br * (nbuk + 1);
    if (threadIdx.x < nbuk) bb[threadIdx.x] = smem[threadIdx.x] - v;
    if (threadIdx.x == nbuk - 1) bb[nbuk] = smem[threadIdx.x];
}

// ---- stage 3: deterministic-slot pair scatter (uint-packed dst|src) ------
__global__ __launch_bounds__(256) void bucket_scatter(
        const int* __restrict__ ei0, const int* __restrict__ ei1,
        const int* __restrict__ carr, const int* __restrict__ bbase,
        unsigned int* __restrict__ pbuf, int nbuk, int E, int tot) {
    __shared__ int base_s[NBKP];
    __shared__ int h[NBKP];
    int br = blockIdx.y;
    const int* ei = br ? ei1 : ei0;
    const int* offb = carr + ((size_t)br * gridDim.x + blockIdx.x) * NBKP;
    const int* bb = bbase + br * (nbuk + 1);
    unsigned int* pb = pbuf + (size_t)br * tot;
    for (int i = threadIdx.x; i < NBKP; i += 256) {
        h[i] = 0;
        base_s[i] = (i < nbuk) ? (bb[i] + offb[i]) : 0;
    }
    __syncthreads();
    for (int t = blockIdx.x * 256 + threadIdx.x; t < tot; t += 256 * 256) {
        int src, dst;
        if (t < E) { src = ei[t]; dst = ei[E + t]; }
        else       { src = dst = t - E; }
        int k = dst >> 6;
        int r = atomicAdd(&h[k], 1);        // LDS rank
        pb[base_s[k] + r] = ((unsigned)dst << 16) | (unsigned)src;
    }
}

// ---- merged dispatch B: bucket_finalize || layer-1 gemm ------------------
__global__ __launch_bounds__(256) void finalize_gemm(
        const unsigned int* __restrict__ pbuf, const int* __restrict__ bbase,
        int* __restrict__ rowptrb, unsigned short* __restrict__ csrb,
        int n, int nbuk, int tot, int np,
        const float* __restrict__ x0, const float* __restrict__ x1,
        const float* __restrict__ W0, const float* __restrict__ W1,
        const f16* __restrict__ wsd,
        f16* __restrict__ hb, float* __restrict__ ssb, float* __restrict__ sdb) {
    if ((int)blockIdx.x < nbuk) {
        if (blockIdx.z == 0)
            finalize_body(pbuf, bbase, rowptrb, csrb, n, nbuk, tot, np,
                          blockIdx.x, blockIdx.y);
    } else {
        gemm_body<float>(x0, x1, W0, W1, wsd, hb, ssb, sdb, n, 128, 4,
                         blockIdx.x - nbuk, blockIdx.y, blockIdx.z, 128, 2);
    }
}

// ---- standalone gemm (layers 2..4) ---------------------------------------
template <typename XT>
__global__ __launch_bounds__(256) void gemm_mfma(
        const XT* __restrict__ x0, const XT* __restrict__ x1,
        const float* __restrict__ W0, const float* __restrict__ W1,
        const f16* __restrict__ wsd,
        f16* __restrict__ hb, float* __restrict__ ssb, float* __restrict__ sdb,
        int n, int fout, int H) {
    gemm_body<XT>(x0, x1, W0, W1, wsd, hb, ssb, sdb, n, fout, H,
                  blockIdx.x, blockIdx.y, blockIdx.z, gridDim.x, gridDim.y);
}

// ---- fused alpha + gather, 128-wide layers: both branches, XCD-split -----
// masked uniform 16-slot chunks (R19): no separate tail path.
__global__ __launch_bounds__(256) void gather128_f(
        const __half2* __restrict__ h2b, const float* __restrict__ ssb,
        const float* __restrict__ sdb, const int* __restrict__ rpb,
        const unsigned short* __restrict__ csrb,
        const float* __restrict__ bias0, const float* __restrict__ bias1,
        f16* __restrict__ outb, int n, int tot, int np, int nbpb) {
    int flat = blockIdx.x;
    int slot = flat & 7, g = flat >> 3;
    int br = slot >> 2;
    int nb = g * 4 + (slot & 3);
    if (nb >= nbpb) return;

    const __half2* h2 = h2b + (size_t)br * n * 64;
    const float* ss = ssb + (size_t)br * n * 4;
    const float* sd = sdb + (size_t)br * n * 4;
    const int* rowptr = rpb + (size_t)br * np;
    const unsigned short* csr = csrb + (size_t)br * tot;
    const float* bias = br ? bias1 : bias0;
    f16* out = outb + (size_t)br * n * 128;

    int wid = threadIdx.x >> 6, lane = threadIdx.x & 63;
    int v = nb * 4 + wid;
    if (v >= n) return;
    int beg = rowptr[v], end = rowptr[v + 1];
    int hd = lane >> 4;
    int sub = lane & 15;
    int hd16 = hd * 16;
    float sd_h = sd[v * 4 + hd];
    int safe = csr[beg];                    // deg >= 1 (self loop)

    float acc0 = 0.f, acc1 = 0.f, den = 0.f;
    for (int i0 = beg; i0 < end; i0 += 16) {
        int cnt = end - i0;                 // >= 1
        int myidx = (sub < cnt) ? (int)csr[i0 + sub] : safe;
        unsigned hv[16];
        #pragma unroll
        for (int j = 0; j < 16; ++j) {
            int s = __shfl(myidx, j);
            hv[j] = *(const unsigned*)&h2[s * 64 + lane];
        }
        float w_reg = 0.f;
        if (sub < cnt) {
            float sc = ss[myidx * 4 + hd] + sd_h;
            sc = fmaxf(sc, 0.2f * sc);
            w_reg = __expf(sc);
        }
        #pragma unroll
        for (int j = 0; j < 16; ++j) {
            float w = __shfl(w_reg, hd16 + j);
            float2 f = __half22float2(*(const __half2*)&hv[j]);
            acc0 = fmaf(w, f.x, acc0);
            acc1 = fmaf(w, f.y, acc1);
            den += w;
        }
    }

    float inv = 1.f / den;
    float2 b2 = ((const float2*)bias)[lane];
    float o0 = fmaxf(fmaf(acc0, inv, b2.x), 0.f);
    float o1 = fmaxf(fmaf(acc1, inv, b2.y), 0.f);
    __half2 ov = __floats2half2_rn(o0, o1);
    *(unsigned int*)&out[v * 128 + 2 * lane] = *(unsigned int*)&ov;
}

// ---- fused alpha + gather, layer 4, BOTH branches -> single d_out write --
__global__ __launch_bounds__(256) void gather64_both(
        const __half* __restrict__ h0, const __half* __restrict__ h1,
        const float* __restrict__ ss0, const float* __restrict__ ss1,
        const float* __restrict__ sd0, const float* __restrict__ sd1,
        const int* __restrict__ rp0, const int* __restrict__ rp1,
        const unsigned short* __restrict__ csr0,
        const unsigned short* __restrict__ csr1,
        const float* __restrict__ bias0, const float* __restrict__ bias1,
        float* __restrict__ out, int n) {
    int wid = threadIdx.x >> 6, lane = threadIdx.x & 63;
    int v = blockIdx.x * 4 + wid;
    if (v >= n) return;
    int sub = lane & 15;
    float og = 0.f;

    #pragma unroll
    for (int br = 0; br < 2; ++br) {
        const __half* h   = br ? h1 : h0;
        const float* ss   = br ? ss1 : ss0;
        const float* sd   = br ? sd1 : sd0;
        const int* rowptr = br ? rp1 : rp0;
        const unsigned short* csr = br ? csr1 : csr0;
        const float* bias = br ? bias1 : bias0;
        int beg = rowptr[v], end = rowptr[v + 1];
        float sd_v = sd[v];
        int safe = csr[beg];
        float acc = 0.f, den = 0.f;
        for (int i0 = beg; i0 < end; i0 += 16) {
            int cnt = end - i0;
            int myidx = (sub < cnt) ? (int)csr[i0 + sub] : safe;
            unsigned short hv[16];
            #pragma unroll
            for (int j = 0; j < 16; ++j) {
                int s = __shfl(myidx, j);
                hv[j] = *(const unsigned short*)&h[s * 64 + lane];
            }
            float w_reg = 0.f;
            if (sub < cnt) {
                float sc = ss[myidx] + sd_v;
                sc = fmaxf(sc, 0.2f * sc);
                w_reg = __expf(sc);
            }
            #pragma unroll
            for (int j = 0; j < 16; ++j) {
                float w = __shfl(w_reg, j);
                float f = __half2float(*(const __half*)&hv[j]);
                acc = fmaf(w, f, acc);
                den += w;
            }
        }
        float o = acc / den + bias[lane];
        og += 0.5f / (1.f + __expf(-o));
    }
    out[(size_t)v * 64 + lane] = og;
}

extern "C" void kernel_launch(void* const* d_in, const int* in_sizes, int n_in,
                              void* d_out, int out_size, void* d_ws, size_t ws_size,
                              hipStream_t stream) {
    const int N = in_sizes[0] / 128;      // 20000
    const int E = in_sizes[1] / 2;        // 320000
    const int TOT = E + N;                // edges incl. self loops
    const int NP = N + 4;                 // rowptr stride
    const int NBUK = (N + 63) >> 6;       // 313 buckets of 64 nodes

    const float* x1 = (const float*)d_in[0];
    const int*   ei1 = (const int*)d_in[1];
    const float* x2 = (const float*)d_in[2];
    const int*   ei2 = (const int*)d_in[3];
    void* const* P0 = d_in + 4;
    void* const* P1 = d_in + 20;

    // workspace layout (8B-aligned chunks)
    char* w = (char*)d_ws;
    f16* bufX = (f16*)w;                 w += (size_t)2 * N * 128 * 2;
    f16* bufH = (f16*)w;                 w += (size_t)2 * N * 128 * 2;
    float* s_src = (float*)w;            w += (size_t)2 * N * 4 * 4;
    float* s_dst = (float*)w;            w += (size_t)2 * N * 4 * 4;
    int* rowptr = (int*)w;               w += (size_t)2 * NP * 4;
    unsigned short* csr_src = (unsigned short*)w;  w += (size_t)2 * TOT * 2 + 4;
    int* carr = (int*)w;                 w += (size_t)2 * NBLK * NBKP * 4;
    int* btot = (int*)w;                 w += (size_t)2 * NBKP * 4;
    int* bbase = (int*)w;                w += (size_t)2 * (NBUK + 1) * 4 + 8;
    unsigned int* pbuf = (unsigned int*)w;  w += (size_t)2 * TOT * 4;
    f16* wsd = (f16*)w;                  w += (size_t)8 * 2048 * 2;

    dim3 blk(256);
    int gWave  = (N + 3) / 4;             // blocks per branch (4 nodes/block)
    int gSplit = 8 * ((gWave + 3) / 4);   // XCD-partitioned dual-branch grid

    // ---- args for merged wsd+count ---------------------------------------
    WsdArgs wa;
    for (int l = 0; l < 4; ++l) {
        int o = (l < 3) ? l * 4 : 12;
        wa.W[l * 2 + 0]  = (const float*)P0[o + 0];
        wa.W[l * 2 + 1]  = (const float*)P1[o + 0];
        wa.as[l * 2 + 0] = (const float*)P0[o + 1];
        wa.as[l * 2 + 1] = (const float*)P1[o + 1];
        wa.ad[l * 2 + 0] = (const float*)P0[o + 2];
        wa.ad[l * 2 + 1] = (const float*)P1[o + 2];
    }

    // ---- CSR build + weight tiles (merged where independent) -------------
    wsd_count<<<dim3(8 + NBLK, 2, 4), blk, 0, stream>>>(
        wa, wsd, ei1, ei2, carr, E, TOT);
    bucket_scan1<<<dim3(NBUK, 2), blk, 0, stream>>>(carr, btot, NBLK);
    bucket_scan2<<<dim3(1, 2), dim3(512), 0, stream>>>(btot, bbase, NBUK);
    bucket_scatter<<<dim3(NBLK, 2), blk, 0, stream>>>(ei1, ei2, carr, bbase,
                                                      pbuf, NBUK, E, TOT);
    // finalize || layer-1 gemm
    finalize_gemm<<<dim3(NBUK + 128, 2, 2), blk, 0, stream>>>(
        pbuf, bbase, rowptr, csr_src, N, NBUK, TOT, NP,
        x1, x2, (const float*)P0[0], (const float*)P1[0],
        wsd + (size_t)0 * 4096, bufH, s_src, s_dst);

    // ---- layer-1 gather, then layers 2..3 --------------------------------
    gather128_f<<<gSplit, blk, 0, stream>>>(
        (const __half2*)bufH, s_src, s_dst, rowptr, csr_src,
        (const float*)P0[3], (const float*)P1[3],
        bufX, N, TOT, NP, gWave);

    for (int l = 1; l < 3; ++l) {
        gemm_mfma<f16><<<dim3(128, 2, 2), blk, 0, stream>>>(
            bufX, bufX + (size_t)N * 128,
            (const float*)P0[l*4+0], (const float*)P1[l*4+0],
            wsd + (size_t)l * 4096, bufH, s_src, s_dst, N, 128, 4);
        gather128_f<<<gSplit, blk, 0, stream>>>(
            (const __half2*)bufH, s_src, s_dst, rowptr, csr_src,
            (const float*)P0[l*4+3], (const float*)P1[l*4+3],
            bufX, N, TOT, NP, gWave);
    }

    // ---- layer 4 (128 -> 1x64, sigmoid, both branches -> d_out) ---------
    gemm_mfma<f16><<<dim3(128, 1, 2), blk, 0, stream>>>(
        bufX, bufX + (size_t)N * 128,
        (const float*)P0[12], (const float*)P1[12],
        wsd + (size_t)3 * 4096, bufH, s_src, s_dst, N, 64, 1);
    gather64_both<<<gWave, blk, 0, stream>>>(
        (const __half*)bufH, (const __half*)(bufH + (size_t)N * 128),
        s_src, s_src + (size_t)N * 4, s_dst, s_dst + (size_t)N * 4,
        rowptr, rowptr + NP, csr_src, csr_src + (size_t)TOT,
        (const float*)P0[15], (const float*)P1[15],
        (float*)d_out, N);
}